// Round 4
// baseline (7672.308 us; speedup 1.0000x reference)
//
#include <hip/hip_runtime.h>
#include <hip/hip_bf16.h>
#include <math.h>

typedef __hip_bfloat16 bf16;
typedef _Float16 f16;
typedef _Float16 f16x8 __attribute__((ext_vector_type(8)));
typedef float f32x4 __attribute__((ext_vector_type(4)));

// ---------------------------------------------------------------- dtype detect
__global__ void k_detect(const unsigned int* __restrict__ w, int nwords, int* __restrict__ flag){
  __shared__ int cnt;
  if(threadIdx.x==0) cnt=0;
  __syncthreads();
  int local=0;
  for(int i=threadIdx.x;i<nwords;i+=256){
    unsigned int v=w[i];
    int e=(v>>7)&0xFF;
    if(e>=0xC0) local++;
  }
  atomicAdd(&cnt, local);
  __syncthreads();
  if(threadIdx.x==0) flag[0] = (cnt > (nwords>>3)) ? 1 : 0;
}

// ---------------------------------------------------------------- converts
__global__ void k_cvt(const void* __restrict__ s, float* __restrict__ d, int n,
                      const int* __restrict__ flag){
  int i = blockIdx.x*256 + threadIdx.x;
  if(i>=n) return;
  if(*flag) d[i] = ((const float*)s)[i];
  else      d[i] = __bfloat162float(((const bf16*)s)[i]);
}

__global__ void k_cvth(const void* __restrict__ s, f16* __restrict__ d, int nsrc, int npad,
                       const int* __restrict__ flag){
  int i = blockIdx.x*256 + threadIdx.x;
  if(i>=npad) return;
  float v=0.f;
  if(i<nsrc) v = (*flag)? ((const float*)s)[i] : __bfloat162float(((const bf16*)s)[i]);
  d[i]=(f16)v;
}

__global__ void k_zero(float* __restrict__ p, int n){
  int i = blockIdx.x*256 + threadIdx.x;
  if(i<n) p[i]=0.f;
}

// ---------------------------------------------------------------- FPS: one wave per problem, no barriers/LDS
// Exact pointnet2 semantics (start idx 0, argmax of running min-dist,
// ties -> smallest index via packed key; contract-off f32 distances).
template<int P>
__global__ __launch_bounds__(64) void k_fps_w(
    const float* __restrict__ xyz, int L, int N, int m,
    int c0,int c1,int c2,int c3, int T, float* __restrict__ anchors)
{
  int prob = blockIdx.x;
  int b = prob / T, tt = prob % T;
  int f = (tt==0)?c0:(tt==1)?c1:(tt==2)?c2:c3;
  const float* src = xyz + ((size_t)(b*L + f))*N*3;
  float* anc = anchors + ((size_t)(b*T + tt))*m*3;
  int lane = threadIdx.x;                 // 64 lanes
  float px[P],py[P],pz[P],mind[P];
#pragma unroll
  for(int j=0;j<P;j++){
    int p = lane + j*64;
    px[j]=src[3*p]; py[j]=src[3*p+1]; pz[j]=src[3*p+2];
    mind[j]=1e10f;
  }
  float lx=__shfl(px[0],0), ly=__shfl(py[0],0), lz=__shfl(pz[0],0);
  if(lane==0){ anc[0]=lx; anc[1]=ly; anc[2]=lz; }
  for(int it=1; it<m; ++it){
    float bv=-1.f, bx=0.f, by=0.f, bz=0.f; int bi=0;
#pragma unroll
    for(int j=0;j<P;j++){
#pragma clang fp contract(off)
      float dx=px[j]-lx, dy=py[j]-ly, dz=pz[j]-lz;
      float d2=dx*dx+dy*dy+dz*dz;
      float mv=mind[j]; if(d2<mv) mv=d2; mind[j]=mv;
      if(mv>bv){ bv=mv; bi=lane+j*64; bx=px[j]; by=py[j]; bz=pz[j]; }
    }
    // packed key: dist (>=0, IEEE order == uint order) | inverted index (tie -> smallest idx)
    unsigned long long key = ((unsigned long long)__float_as_uint(bv)<<32)
                           | (unsigned long long)(0xFFFFFFFFu - (unsigned)bi);
#pragma unroll
    for(int o=32;o>0;o>>=1){
      unsigned long long ok=__shfl_xor(key,o);
      float ox=__shfl_xor(bx,o), oy=__shfl_xor(by,o), oz=__shfl_xor(bz,o);
      if(ok>key){ key=ok; bx=ox; by=oy; bz=oz; }
    }
    lx=bx; ly=by; lz=bz;                   // winner coords, wave-uniform
    if(lane==0){ anc[3*it]=bx; anc[3*it+1]=by; anc[3*it+2]=bz; }
  }
}

// ---------------------------------------------------------------- ball query (exact f32)
__global__ __launch_bounds__(256) void k_bq(
    const float* __restrict__ pts, const float* __restrict__ anc,
    int* __restrict__ out, int N, int m, float r2,
    size_t pBS, size_t aBS)
{
  int chunks = (m+255)>>8;
  int b = blockIdx.x / chunks;
  int a = (blockIdx.x % chunks)*256 + threadIdx.x;
  const float* Pb = pts + (size_t)b*pBS;
  bool act = a < m;
  float ax=0,ay=0,az=0;
  int* o = out + ((size_t)b*m + (size_t)(act?a:0))*9;
  if(act){ const float* A = anc + (size_t)b*aBS + (size_t)a*3; ax=A[0]; ay=A[1]; az=A[2]; }
  int cnt = act?0:9, first=0;
  __shared__ float sp[768];
  for(int base=0; base<N; base+=256){
    for(int t=threadIdx.x; t<768; t+=256) sp[t]=Pb[(size_t)base*3+t];
    __syncthreads();
    for(int q=0;q<256;q++){
#pragma clang fp contract(off)
      float dx=sp[3*q]-ax, dy=sp[3*q+1]-ay, dz=sp[3*q+2]-az;
      float d2=dx*dx+dy*dy+dz*dz;
      if(d2<r2 && cnt<9){
        int p=base+q;
        if(cnt==0) first=p;
        o[cnt]=p; cnt++;
      }
    }
    if(__syncthreads_and(cnt>=9)) break;
  }
  if(act){ for(int k=cnt;k<9;k++) o[k]=first; }
}

// ---------------------------------------------------------------- layer 0 part (f32)
__global__ void k_part0(
    const float* __restrict__ pts, const float* __restrict__ anc,
    const int* __restrict__ idx, const float* __restrict__ Wd,
    float* __restrict__ nf, int m, int mid, int ld, int nmask,
    size_t pBS, size_t aBS)
{
  int row = blockIdx.x;
  int b = row/m, mm = row - b*m;
  int o = threadIdx.x;
  const float* A = anc + (size_t)b*aBS + (size_t)mm*3;
  float ax=A[0], ay=A[1], az=A[2];
  float w0=0,w1=0,w2=0;
  if(o<mid){ w0=Wd[3*o]; w1=Wd[3*o+1]; w2=Wd[3*o+2]; }
  const int* id = idx + (size_t)row*9;
  const float* Pb = pts + (size_t)b*pBS;
  float acc=0.f;
  for(int k=0;k<9;k++){
    int p=id[k] & nmask;
    const float* q = Pb + (size_t)p*3;
    float dx=q[0]-ax, dy=q[1]-ay, dz=q[2]-az;
    acc += dx*w0+dy*w1+dz*w2;
  }
  if(o<mid) nf[(size_t)row*ld + o] = acc;
}

// ---------------------------------------------------------------- MFMA pair kernel
__global__ __launch_bounds__(256) void k_pair_mfma(
    const float* __restrict__ feats, const float* __restrict__ pts,
    const float* __restrict__ anc, const int* __restrict__ idx,
    const f16* __restrict__ Wfh, const float* __restrict__ Wd,
    float* __restrict__ nf, int m, int cin, int mid, int ld, int jofs, int nmask,
    size_t fBS, size_t pBS, size_t aBS)
{
  __shared__ f16 As[128*40];       // 80B row pitch -> 2-way bank aliasing (free)
  __shared__ f16 Bs[128*40];
  __shared__ float dispS[128][4];
  __shared__ float ancS[128][3];
  __shared__ int  idxS[128];
  int tid=threadIdx.x;
  int lane=tid&63, w=tid>>6;
  int quad=lane>>4, l15=lane&15;
  int rowOff=(w>>1)*64, colOff=(w&1)*64;
  int rowBase=blockIdx.x*128, colBase=blockIdx.y*128;
  int b=rowBase/m;
  const float* fB=feats+(size_t)b*fBS;
  const float* pB=pts+(size_t)b*pBS;
  if(tid<128){
    int mm=(rowBase+tid)-b*m;
    const float* A0=anc+(size_t)b*aBS+(size_t)mm*3;
    ancS[tid][0]=A0[0]; ancS[tid][1]=A0[1]; ancS[tid][2]=A0[2];
  }
  float wdv[4][3];
#pragma unroll
  for(int ctl=0;ctl<4;ctl++){
    int col=colBase+colOff+ctl*16+l15;
    if(col<mid){ wdv[ctl][0]=Wd[3*col]; wdv[ctl][1]=Wd[3*col+1]; wdv[ctl][2]=Wd[3*col+2]; }
    else { wdv[ctl][0]=0.f; wdv[ctl][1]=0.f; wdv[ctl][2]=0.f; }
  }
  f32x4 acc[4][4];
#pragma unroll
  for(int i=0;i<4;i++)
#pragma unroll
    for(int j=0;j<4;j++) acc[i][j]=(f32x4){0.f,0.f,0.f,0.f};
  int nct=cin>>5;
  int srow=tid>>1, shalf=tid&1;
  const int* idxB = idx + (size_t)rowBase*9;
  for(int k=0;k<9;k++){
    __syncthreads();
    if(tid<128){
      int p=idxB[tid*9+k]&nmask;
      idxS[tid]=p;
      const float* q=pB+(size_t)p*3;
      dispS[tid][0]=q[0]-ancS[tid][0];
      dispS[tid][1]=q[1]-ancS[tid][1];
      dispS[tid][2]=q[2]-ancS[tid][2];
      dispS[tid][3]=0.f;
    }
    f32x4 S[4][4];
#pragma unroll
    for(int i=0;i<4;i++)
#pragma unroll
      for(int j=0;j<4;j++) S[i][j]=(f32x4){0.f,0.f,0.f,0.f};
    for(int ct=0;ct<nct;ct++){
      __syncthreads();
      {
        int p=idxS[srow];
        const float* src=fB+(size_t)p*cin+(ct<<5)+(shalf<<4);
        float4 v0=((const float4*)src)[0];
        float4 v1=((const float4*)src)[1];
        float4 v2=((const float4*)src)[2];
        float4 v3=((const float4*)src)[3];
        f16x8 h0, h1;
        h0[0]=(f16)v0.x; h0[1]=(f16)v0.y; h0[2]=(f16)v0.z; h0[3]=(f16)v0.w;
        h0[4]=(f16)v1.x; h0[5]=(f16)v1.y; h0[6]=(f16)v1.z; h0[7]=(f16)v1.w;
        h1[0]=(f16)v2.x; h1[1]=(f16)v2.y; h1[2]=(f16)v2.z; h1[3]=(f16)v2.w;
        h1[4]=(f16)v3.x; h1[5]=(f16)v3.y; h1[6]=(f16)v3.z; h1[7]=(f16)v3.w;
        *(f16x8*)(As + srow*40 + (shalf<<4))     = h0;
        *(f16x8*)(As + srow*40 + (shalf<<4) + 8) = h1;
      }
      {
        const uint4* s=(const uint4*)(Wfh+(size_t)(colBase+srow)*cin+(ct<<5)+(shalf<<4));
        uint4 u0=s[0], u1=s[1];
        *(uint4*)(Bs + srow*40 + (shalf<<4))     = u0;
        *(uint4*)(Bs + srow*40 + (shalf<<4) + 8) = u1;
      }
      __syncthreads();
      f16x8 af[4], bf4[4];
#pragma unroll
      for(int rt=0;rt<4;rt++) af[rt]=*(const f16x8*)(As + (rowOff+rt*16+l15)*40 + quad*8);
#pragma unroll
      for(int ctl=0;ctl<4;ctl++) bf4[ctl]=*(const f16x8*)(Bs + (colOff+ctl*16+l15)*40 + quad*8);
#pragma unroll
      for(int rt=0;rt<4;rt++)
#pragma unroll
        for(int ctl=0;ctl<4;ctl++)
          S[rt][ctl]=__builtin_amdgcn_mfma_f32_16x16x32_f16(af[rt],bf4[ctl],S[rt][ctl],0,0,0);
    }
#pragma unroll
    for(int rt=0;rt<4;rt++){
#pragma unroll
      for(int r=0;r<4;r++){
        int rl=rowOff+rt*16+quad*4+r;
        float4 dv=*(const float4*)dispS[rl];
#pragma unroll
        for(int ctl=0;ctl<4;ctl++){
          float d=dv.x*wdv[ctl][0]+dv.y*wdv[ctl][1]+dv.z*wdv[ctl][2];
          acc[rt][ctl][r]+=S[rt][ctl][r]*d;
        }
      }
    }
  }
#pragma unroll
  for(int rt=0;rt<4;rt++){
#pragma unroll
    for(int r=0;r<4;r++){
      int row=rowBase+rowOff+rt*16+quad*4+r;
#pragma unroll
      for(int ctl=0;ctl<4;ctl++){
        int col=colBase+colOff+ctl*16+l15;
        if(col<mid) nf[(size_t)row*ld + jofs + col]=acc[rt][ctl][r];
      }
    }
  }
}

// ---------------------------------------------------------------- MFMA GEMM
template<bool RELU, bool DYN>
__global__ __launch_bounds__(256) void k_gemm_mfma(
    const float* __restrict__ Ag, const f16* __restrict__ Bh,
    const float* __restrict__ bias, void* __restrict__ out,
    int M, int K, int N, int mloc, size_t oBS, const int* __restrict__ oflag)
{
  __shared__ f16 As[128*40];
  __shared__ f16 Bs[128*40];
  int tid=threadIdx.x;
  int lane=tid&63, w=tid>>6;
  int quad=lane>>4, l15=lane&15;
  int rowOff=(w>>1)*64, colOff=(w&1)*64;
  int rowBase=blockIdx.x*128, colBase=blockIdx.y*128;
  f32x4 acc[4][4];
#pragma unroll
  for(int i=0;i<4;i++)
#pragma unroll
    for(int j=0;j<4;j++) acc[i][j]=(f32x4){0.f,0.f,0.f,0.f};
  int nct=K>>5;
  int srow=tid>>1, shalf=tid&1;
  for(int ct=0;ct<nct;ct++){
    __syncthreads();
    {
      const float* src=Ag+(size_t)(rowBase+srow)*K+(ct<<5)+(shalf<<4);
      float4 v0=((const float4*)src)[0];
      float4 v1=((const float4*)src)[1];
      float4 v2=((const float4*)src)[2];
      float4 v3=((const float4*)src)[3];
      f16x8 h0, h1;
      h0[0]=(f16)v0.x; h0[1]=(f16)v0.y; h0[2]=(f16)v0.z; h0[3]=(f16)v0.w;
      h0[4]=(f16)v1.x; h0[5]=(f16)v1.y; h0[6]=(f16)v1.z; h0[7]=(f16)v1.w;
      h1[0]=(f16)v2.x; h1[1]=(f16)v2.y; h1[2]=(f16)v2.z; h1[3]=(f16)v2.w;
      h1[4]=(f16)v3.x; h1[5]=(f16)v3.y; h1[6]=(f16)v3.z; h1[7]=(f16)v3.w;
      *(f16x8*)(As + srow*40 + (shalf<<4))     = h0;
      *(f16x8*)(As + srow*40 + (shalf<<4) + 8) = h1;
    }
    {
      const uint4* s=(const uint4*)(Bh+(size_t)(colBase+srow)*K+(ct<<5)+(shalf<<4));
      uint4 u0=s[0], u1=s[1];
      *(uint4*)(Bs + srow*40 + (shalf<<4))     = u0;
      *(uint4*)(Bs + srow*40 + (shalf<<4) + 8) = u1;
    }
    __syncthreads();
    f16x8 af[4], bf4[4];
#pragma unroll
    for(int rt=0;rt<4;rt++) af[rt]=*(const f16x8*)(As + (rowOff+rt*16+l15)*40 + quad*8);
#pragma unroll
    for(int ctl=0;ctl<4;ctl++) bf4[ctl]=*(const f16x8*)(Bs + (colOff+ctl*16+l15)*40 + quad*8);
#pragma unroll
    for(int rt=0;rt<4;rt++)
#pragma unroll
      for(int ctl=0;ctl<4;ctl++)
        acc[rt][ctl]=__builtin_amdgcn_mfma_f32_16x16x32_f16(af[rt],bf4[ctl],acc[rt][ctl],0,0,0);
  }
  bool f32m = DYN ? (*oflag!=0) : true;
#pragma unroll
  for(int rt=0;rt<4;rt++){
#pragma unroll
    for(int r=0;r<4;r++){
      int row=rowBase+rowOff+rt*16+quad*4+r;
      int rb=row/mloc, rm=row-rb*mloc;
      size_t obase=(size_t)rb*oBS + (size_t)rm*N;
#pragma unroll
      for(int ctl=0;ctl<4;ctl++){
        int col=colBase+colOff+ctl*16+l15;
        float v=acc[rt][ctl][r];
        if(bias) v+=bias[col];
        if(RELU) v=fmaxf(v,0.f);
        if(DYN && !f32m) ((bf16*)out)[obase+col]=__float2bfloat16(v);
        else             ((float*)out)[obase+col]=v;
      }
    }
  }
}

// ---------------------------------------------------------------- BatchNorm
__global__ void k_bnstat(const float* __restrict__ nf, int M, int C, float* __restrict__ sums){
  int c = blockIdx.x*256 + threadIdx.x;
  if(c>=C) return;
  int rows = M>>5;
  int r0 = blockIdx.y*rows, r1 = r0+rows;
  float s=0.f, s2=0.f;
  for(int r=r0;r<r1;r++){
    float v=nf[(size_t)r*C+c];
    s+=v; s2+=v*v;
  }
  atomicAdd(&sums[c], s);
  atomicAdd(&sums[C+c], s2);
}

__global__ void k_bnapply(float* __restrict__ nf, const float* __restrict__ sums, int M, int C){
  long long i = (long long)blockIdx.x*256 + threadIdx.x;
  long long tot = (long long)M*C;
  if(i>=tot) return;
  int c = (int)(i % (long long)C);
  float mean = sums[c]/(float)M;
  float var = sums[C+c]/(float)M - mean*mean;
  if(var<0.f) var=0.f;
  float v = (nf[i]-mean)/sqrtf(var+1e-5f);
  nf[i] = v>0.f? v:0.f;
}

// ---------------------------------------------------------------- f32 GEMM (layer 0 temporal, K=45)
template<int TN, bool ALIGNED, bool RELU>
__global__ __launch_bounds__(256) void k_gemm(
    const float* __restrict__ Ag, const float* __restrict__ Wg,
    const float* __restrict__ bias, float* __restrict__ out,
    int M, int K, int N, int mloc, size_t oBS)
{
  constexpr int CW = TN/16;
  __shared__ alignas(16) float As[16][64];
  __shared__ alignas(16) float Bs[16][TN];
  int tid=threadIdx.x, tx=tid&15, ty=tid>>4;
  int rowBase=blockIdx.x*64, colBase=blockIdx.y*TN;
  float acc[4][CW];
#pragma unroll
  for(int i=0;i<4;i++)
#pragma unroll
    for(int j=0;j<CW;j++) acc[i][j]=0.f;
  int lrow=tid&63, lcq=tid>>6;
  int nct=(K+15)>>4;
  for(int ct=0;ct<nct;ct++){
    __syncthreads();
    {
      int r=rowBase+lrow, c0=(ct<<4)+(lcq<<2);
#pragma unroll
      for(int q=0;q<4;q++){
        int c=c0+q;
        As[(lcq<<2)+q][lrow] = (ALIGNED||c<K)? Ag[(size_t)r*K+c] : 0.f;
      }
    }
    {
      int og=colBase+lrow, c0=(ct<<4)+(lcq<<2);
#pragma unroll
      for(int q=0;q<4;q++){
        int c=c0+q;
        Bs[(lcq<<2)+q][lrow] = (ALIGNED||c<K)? Wg[(size_t)og*K+c] : 0.f;
      }
    }
    __syncthreads();
#pragma unroll
    for(int c=0;c<16;c++){
      float4 a4=*(const float4*)&As[c][ty<<2];
      float av[4]={a4.x,a4.y,a4.z,a4.w};
      float bw[CW];
#pragma unroll
      for(int j0=0;j0<CW;j0+=4){
        float4 b4=*(const float4*)&Bs[c][tx*CW+j0];
        bw[j0]=b4.x; bw[j0+1]=b4.y; bw[j0+2]=b4.z; bw[j0+3]=b4.w;
      }
#pragma unroll
      for(int i=0;i<4;i++)
#pragma unroll
        for(int j=0;j<CW;j++) acc[i][j]+=av[i]*bw[j];
    }
  }
#pragma unroll
  for(int i=0;i<4;i++){
    int r=rowBase+(ty<<2)+i;
    int rb=r/mloc, rm=r-rb*mloc;
    size_t obase=(size_t)rb*oBS + (size_t)rm*N;
#pragma unroll
    for(int j=0;j<CW;j++){
      int o=colBase+tx*CW+j;
      float v=acc[i][j];
      if(bias) v+=bias[o];
      if(RELU) v=fmaxf(v,0.f);
      out[obase+o]=v;
    }
  }
}

// ---------------------------------------------------------------- host
extern "C" void kernel_launch(void* const* d_in, const int* in_sizes, int n_in,
                              void* d_out, int out_size, void* d_ws, size_t ws_size,
                              hipStream_t stream) {
  (void)in_sizes; (void)n_in; (void)out_size; (void)ws_size;

  const int di[6] = {2,4,7,10,13,16};
  const int fi[6] = {-1,5,8,11,14,17};
  const int ti[6] = {3,6,9,12,15,18};

  const int midv[6]={45,96,192,384,768,1536};
  const int midp[6]={0,128,256,384,768,1536};
  const int cinv[6]={0,64,128,256,512,1024};
  const int coutv[6]={64,128,256,512,1024,2048};
  const int tkv[6]={1,3,3,3,3,1};
  const int Nv[6]={2048,1024,512,512,256,256};
  const int mv[6]={1024,512,512,256,256,128};
  const int Lv[6]={4,4,2,2,1,1};
  const int Tv[6]={4,2,2,1,1,1};
  const float rrv[6]={1.5f,3.f,3.f,6.f,6.f,6.f};

  float* ws=(float*)d_ws;
  size_t off=0;
  auto A=[&](size_t n)->float*{ float* p=ws+off; off+=(n+63)&~(size_t)63; return p; };
  auto Ah=[&](size_t n)->f16*{ return (f16*)A((n+1)/2); };

  int* flag=(int*)A(64);

  float *Wd[6]; f16 *Wfh[6], *Wth[6];
  float* Wt0;
  for(int l=0;l<6;l++){
    Wd[l]=A((size_t)midv[l]*3);
    Wfh[l]= cinv[l]? Ah((size_t)midp[l]*cinv[l]) : nullptr;
    Wth[l]= l? Ah((size_t)coutv[l]*tkv[l]*midv[l]) : nullptr;
  }
  Wt0=A((size_t)64*45);
  f16* fcwh=Ah(1024ull*2048);
  float* fcb=A(1024);

  float* X[7];
  X[0]=A(32ull*4*2048*3);
  for(int l=0;l<6;l++) X[l+1]=A((size_t)32*Tv[l]*mv[l]*3);

  float* FA=A(8388608);
  float* FB=A(8388608);
  float* F[7]; F[0]=nullptr;
  for(int l=0;l<6;l++) F[l+1]=(l%2==0)?FA:FB;

  float* nf=A(18874368);
  float* sums=A(4608);
  int* bq=(int*)A(32ull*1024*9);

  k_detect<<<dim3(1),dim3(256),0,stream>>>((const unsigned int*)d_in[0], 4096, flag);

  auto cvt=[&](const void* s, float* d, size_t n){
    k_cvt<<<dim3((unsigned)((n+255)/256)),dim3(256),0,stream>>>(s,d,(int)n,flag);
  };
  auto cvth=[&](const void* s, f16* d, size_t nsrc, size_t npad){
    k_cvth<<<dim3((unsigned)((npad+255)/256)),dim3(256),0,stream>>>(s,d,(int)nsrc,(int)npad,flag);
  };
  cvt(d_in[0], X[0], 32ull*4*2048*3);
  for(int l=0;l<6;l++){
    cvt(d_in[di[l]], Wd[l], (size_t)midv[l]*3);
    if(cinv[l]) cvth(d_in[fi[l]], Wfh[l], (size_t)midv[l]*cinv[l], (size_t)midp[l]*cinv[l]);
    if(l) cvth(d_in[ti[l]], Wth[l], (size_t)coutv[l]*tkv[l]*midv[l], (size_t)coutv[l]*tkv[l]*midv[l]);
  }
  cvt(d_in[3], Wt0, 64*45);
  cvth(d_in[19], fcwh, 1024ull*2048, 1024ull*2048);
  cvt(d_in[20], fcb, 1024);

  struct PairT{int j,i;};
  const int Tcenters[6][4]={{0,1,2,3},{0,2,0,0},{0,1,0,0},{0,0,0,0},{0,0,0,0},{0,0,0,0}};
  const int npairs[6][4]={{1,1,1,1},{2,3,0,0},{2,2,0,0},{2,0,0,0},{1,0,0,0},{1,0,0,0}};
  const PairT pr[6][4][3]={
    { {{0,0},{0,0},{0,0}}, {{0,1},{0,0},{0,0}}, {{0,2},{0,0},{0,0}}, {{0,3},{0,0},{0,0}} },
    { {{1,0},{2,1},{0,0}}, {{0,1},{1,2},{2,3}}, {{0,0},{0,0},{0,0}}, {{0,0},{0,0},{0,0}} },
    { {{1,0},{2,1},{0,0}}, {{0,0},{1,1},{0,0}}, {{0,0},{0,0},{0,0}}, {{0,0},{0,0},{0,0}} },
    { {{1,0},{2,1},{0,0}}, {{0,0},{0,0},{0,0}}, {{0,0},{0,0},{0,0}}, {{0,0},{0,0},{0,0}} },
    { {{1,0},{0,0},{0,0}}, {{0,0},{0,0},{0,0}}, {{0,0},{0,0},{0,0}}, {{0,0},{0,0},{0,0}} },
    { {{0,0},{0,0},{0,0}}, {{0,0},{0,0},{0,0}}, {{0,0},{0,0},{0,0}}, {{0,0},{0,0},{0,0}} },
  };

  for(int l=0;l<6;l++){
    int N=Nv[l], m=mv[l], Lin=Lv[l], T=Tv[l], cin=cinv[l], mid=midv[l];
    int C=tkv[l]*midv[l], M=32*m, cout=coutv[l];
    float r2=rrv[l]*rrv[l];
    const float* Xin=X[l]; float* Xout=X[l+1];

    {
      dim3 g(32*T), blk(64);
      int a0=Tcenters[l][0],a1=Tcenters[l][1],a2=Tcenters[l][2],a3=Tcenters[l][3];
      if(N==2048)      k_fps_w<32><<<g,blk,0,stream>>>(Xin,Lin,N,m,a0,a1,a2,a3,T,Xout);
      else if(N==1024) k_fps_w<16><<<g,blk,0,stream>>>(Xin,Lin,N,m,a0,a1,a2,a3,T,Xout);
      else if(N==512)  k_fps_w<8><<<g,blk,0,stream>>>(Xin,Lin,N,m,a0,a1,a2,a3,T,Xout);
      else             k_fps_w<4><<<g,blk,0,stream>>>(Xin,Lin,N,m,a0,a1,a2,a3,T,Xout);
    }

    for(int tt=0; tt<T; ++tt){
      k_zero<<<dim3((unsigned)(((size_t)M*C+255)/256)),256,0,stream>>>(nf,(int)((size_t)M*C));
      k_zero<<<dim3((unsigned)((2*C+255)/256)),256,0,stream>>>(sums,2*C);
      const float* anc = Xout + (size_t)tt*m*3;
      size_t aBS=(size_t)T*m*3;
      for(int pi=0; pi<npairs[l][tt]; ++pi){
        int j=pr[l][tt][pi].j, i=pr[l][tt][pi].i;
        const float* pts = Xin + (size_t)i*N*3;
        size_t pBS=(size_t)Lin*N*3;
        int chunks=(m+255)>>8;
        k_bq<<<dim3(32*chunks),256,0,stream>>>(pts,anc,bq,N,m,r2,pBS,aBS);
        if(l==0){
          k_part0<<<dim3(M),64,0,stream>>>(pts,anc,bq,Wd[0],nf,m,mid,C,N-1,pBS,aBS);
        } else {
          const float* fin = F[l] + (size_t)i*N*cin;
          size_t fBS=(size_t)Lin*N*cin;
          k_pair_mfma<<<dim3(M/128, midp[l]/128),256,0,stream>>>(
              fin,pts,anc,bq,Wfh[l],Wd[l],nf,m,cin,mid,C,j*mid,N-1,fBS,pBS,aBS);
        }
      }
      k_bnstat<<<dim3((C+255)/256,32),256,0,stream>>>(nf,M,C,sums);
      k_bnapply<<<dim3((unsigned)(((size_t)M*C+255)/256)),256,0,stream>>>(nf,sums,M,C);
      float* outp = F[l+1] + (size_t)tt*m*cout;
      size_t oBS=(size_t)T*m*cout;
      if(l==0)
        k_gemm<64,false,true><<<dim3(M/64,cout/64),256,0,stream>>>(nf,Wt0,nullptr,outp,M,C,cout,m,oBS);
      else if(l<5)
        k_gemm_mfma<true,false><<<dim3(M/128,cout/128),256,0,stream>>>(nf,Wth[l],nullptr,outp,M,C,cout,m,oBS,nullptr);
      else
        k_gemm_mfma<false,false><<<dim3(M/128,cout/128),256,0,stream>>>(nf,Wth[l],nullptr,outp,M,C,cout,m,oBS,nullptr);
    }
  }

  k_gemm_mfma<false,true><<<dim3(4096/128,1024/128),256,0,stream>>>(
      F[6],fcwh,fcb,d_out,4096,2048,1024,128,(size_t)128*1024,flag);
}

// Round 5
// 6051.079 us; speedup vs baseline: 1.2679x; 1.2679x over previous
//
#include <hip/hip_runtime.h>
#include <hip/hip_bf16.h>
#include <math.h>

typedef __hip_bfloat16 bf16;
typedef _Float16 f16;
typedef _Float16 f16x8 __attribute__((ext_vector_type(8)));
typedef float f32x4 __attribute__((ext_vector_type(4)));

// ---------------------------------------------------------------- dtype detect
__global__ void k_detect(const unsigned int* __restrict__ w, int nwords, int* __restrict__ flag){
  __shared__ int cnt;
  if(threadIdx.x==0) cnt=0;
  __syncthreads();
  int local=0;
  for(int i=threadIdx.x;i<nwords;i+=256){
    unsigned int v=w[i];
    int e=(v>>7)&0xFF;
    if(e>=0xC0) local++;
  }
  atomicAdd(&cnt, local);
  __syncthreads();
  if(threadIdx.x==0) flag[0] = (cnt > (nwords>>3)) ? 1 : 0;
}

// ---------------------------------------------------------------- converts
__global__ void k_cvt(const void* __restrict__ s, float* __restrict__ d, int n,
                      const int* __restrict__ flag){
  int i = blockIdx.x*256 + threadIdx.x;
  if(i>=n) return;
  if(*flag) d[i] = ((const float*)s)[i];
  else      d[i] = __bfloat162float(((const bf16*)s)[i]);
}

__global__ void k_cvth(const void* __restrict__ s, f16* __restrict__ d, int nsrc, int npad,
                       const int* __restrict__ flag){
  int i = blockIdx.x*256 + threadIdx.x;
  if(i>=npad) return;
  float v=0.f;
  if(i<nsrc) v = (*flag)? ((const float*)s)[i] : __bfloat162float(((const bf16*)s)[i]);
  d[i]=(f16)v;
}

__global__ void k_zero(float* __restrict__ p, int n){
  int i = blockIdx.x*256 + threadIdx.x;
  if(i<n) p[i]=0.f;
}

// ---------------------------------------------------------------- FPS v3: 256 threads, DPP in-wave argmax,
// one barrier/iter (double-buffered cross-wave keys), coords by LDS index lookup.
// Exact pointnet2 semantics: start idx 0, argmax of running min-dist, tie -> smallest index
// (packed key: f32 dist bits | inverted index). Contract-off f32 distances.
template<int P>
__global__ __launch_bounds__(256) void k_fps2(
    const float* __restrict__ xyz, int L, int N, int m,
    int c0,int c1,int c2,int c3, int T, float* __restrict__ anchors)
{
  __shared__ float4 ptsS[P*256];
  __shared__ unsigned long long keyS[2][4];
  int prob=blockIdx.x;
  int b=prob/T, tt=prob%T;
  int f=(tt==0)?c0:(tt==1)?c1:(tt==2)?c2:c3;
  const float* src = xyz + ((size_t)(b*L+f))*N*3;
  float* anc = anchors + ((size_t)(b*T+tt))*m*3;
  int tid=threadIdx.x;
  for(int t=tid;t<N;t+=256)
    ptsS[t]=make_float4(src[3*t],src[3*t+1],src[3*t+2],0.f);
  __syncthreads();
  float px[P],py[P],pz[P],mind[P];
#pragma unroll
  for(int j=0;j<P;j++){
    float4 v=ptsS[tid+j*256];
    px[j]=v.x; py[j]=v.y; pz[j]=v.z; mind[j]=1e10f;
  }
  float4 p0=ptsS[0];
  float lx=p0.x, ly=p0.y, lz=p0.z;
  if(tid==0){ anc[0]=lx; anc[1]=ly; anc[2]=lz; }
  int w=tid>>6;
  for(int it=1; it<m; ++it){
    float bv=-1.f; int bi=0;
#pragma unroll
    for(int j=0;j<P;j++){
#pragma clang fp contract(off)
      float dx=px[j]-lx, dy=py[j]-ly, dz=pz[j]-lz;
      float d2=dx*dx+dy*dy+dz*dz;
      float mv=mind[j]; if(d2<mv) mv=d2; mind[j]=mv;
      if(mv>bv){ bv=mv; bi=tid+j*256; }
    }
    unsigned int hi=__float_as_uint(bv);          // dist >= 0: IEEE order == uint order
    unsigned int lo=0xFFFFFFFFu-(unsigned)bi;     // bigger lo == smaller index
    // DPP max-scan: row_shr 1,2,4,8 then row_bcast 15,31 -> lane 63 holds wave max.
    // Invalid source lanes yield 0 (bound_ctrl), key=0 never wins (lo>0 for real keys).
#define DPPSTEP(CTRL) { \
    unsigned int shi=(unsigned)__builtin_amdgcn_update_dpp(0,(int)hi,CTRL,0xF,0xF,true); \
    unsigned int slo=(unsigned)__builtin_amdgcn_update_dpp(0,(int)lo,CTRL,0xF,0xF,true); \
    bool g=(shi>hi)||(shi==hi&&slo>lo); \
    hi=g?shi:hi; lo=g?slo:lo; }
    DPPSTEP(0x111) DPPSTEP(0x112) DPPSTEP(0x114) DPPSTEP(0x118) DPPSTEP(0x142) DPPSTEP(0x143)
#undef DPPSTEP
    if((tid&63)==63)
      keyS[it&1][w]=((unsigned long long)hi<<32)|lo;
    __syncthreads();
    unsigned long long k0=keyS[it&1][0], k1=keyS[it&1][1];
    unsigned long long k2=keyS[it&1][2], k3=keyS[it&1][3];
    unsigned long long ka = k0>k1?k0:k1;
    unsigned long long kb = k2>k3?k2:k3;
    unsigned long long kk = ka>kb?ka:kb;
    int wi = (int)(0xFFFFFFFFu - (unsigned)(kk & 0xFFFFFFFFull));
    float4 wc = ptsS[wi];
    lx=wc.x; ly=wc.y; lz=wc.z;
    if(tid==0){ anc[3*it]=lx; anc[3*it+1]=ly; anc[3*it+2]=lz; }
  }
}

// ---------------------------------------------------------------- ball query (exact f32)
__global__ __launch_bounds__(256) void k_bq(
    const float* __restrict__ pts, const float* __restrict__ anc,
    int* __restrict__ out, int N, int m, float r2,
    size_t pBS, size_t aBS)
{
  int chunks = (m+255)>>8;
  int b = blockIdx.x / chunks;
  int a = (blockIdx.x % chunks)*256 + threadIdx.x;
  const float* Pb = pts + (size_t)b*pBS;
  bool act = a < m;
  float ax=0,ay=0,az=0;
  int* o = out + ((size_t)b*m + (size_t)(act?a:0))*9;
  if(act){ const float* A = anc + (size_t)b*aBS + (size_t)a*3; ax=A[0]; ay=A[1]; az=A[2]; }
  int cnt = act?0:9, first=0;
  __shared__ float sp[768];
  for(int base=0; base<N; base+=256){
    for(int t=threadIdx.x; t<768; t+=256) sp[t]=Pb[(size_t)base*3+t];
    __syncthreads();
    for(int q=0;q<256;q++){
#pragma clang fp contract(off)
      float dx=sp[3*q]-ax, dy=sp[3*q+1]-ay, dz=sp[3*q+2]-az;
      float d2=dx*dx+dy*dy+dz*dz;
      if(d2<r2 && cnt<9){
        int p=base+q;
        if(cnt==0) first=p;
        o[cnt]=p; cnt++;
      }
    }
    if(__syncthreads_and(cnt>=9)) break;
  }
  if(act){ for(int k=cnt;k<9;k++) o[k]=first; }
}

// ---------------------------------------------------------------- layer 0 part (f32)
__global__ void k_part0(
    const float* __restrict__ pts, const float* __restrict__ anc,
    const int* __restrict__ idx, const float* __restrict__ Wd,
    float* __restrict__ nf, int m, int mid, int ld, int nmask,
    size_t pBS, size_t aBS)
{
  int row = blockIdx.x;
  int b = row/m, mm = row - b*m;
  int o = threadIdx.x;
  const float* A = anc + (size_t)b*aBS + (size_t)mm*3;
  float ax=A[0], ay=A[1], az=A[2];
  float w0=0,w1=0,w2=0;
  if(o<mid){ w0=Wd[3*o]; w1=Wd[3*o+1]; w2=Wd[3*o+2]; }
  const int* id = idx + (size_t)row*9;
  const float* Pb = pts + (size_t)b*pBS;
  float acc=0.f;
  for(int k=0;k<9;k++){
    int p=id[k] & nmask;
    const float* q = Pb + (size_t)p*3;
    float dx=q[0]-ax, dy=q[1]-ay, dz=q[2]-az;
    acc += dx*w0+dy*w1+dz*w2;
  }
  if(o<mid) nf[(size_t)row*ld + o] = acc;
}

// ---------------------------------------------------------------- MFMA pair kernel
__global__ __launch_bounds__(256) void k_pair_mfma(
    const float* __restrict__ feats, const float* __restrict__ pts,
    const float* __restrict__ anc, const int* __restrict__ idx,
    const f16* __restrict__ Wfh, const float* __restrict__ Wd,
    float* __restrict__ nf, int m, int cin, int mid, int ld, int jofs, int nmask,
    size_t fBS, size_t pBS, size_t aBS)
{
  __shared__ f16 As[128*40];       // 80B row pitch -> 2-way bank aliasing (free)
  __shared__ f16 Bs[128*40];
  __shared__ float dispS[128][4];
  __shared__ float ancS[128][3];
  __shared__ int  idxS[128];
  int tid=threadIdx.x;
  int lane=tid&63, w=tid>>6;
  int quad=lane>>4, l15=lane&15;
  int rowOff=(w>>1)*64, colOff=(w&1)*64;
  int rowBase=blockIdx.x*128, colBase=blockIdx.y*128;
  int b=rowBase/m;
  const float* fB=feats+(size_t)b*fBS;
  const float* pB=pts+(size_t)b*pBS;
  if(tid<128){
    int mm=(rowBase+tid)-b*m;
    const float* A0=anc+(size_t)b*aBS+(size_t)mm*3;
    ancS[tid][0]=A0[0]; ancS[tid][1]=A0[1]; ancS[tid][2]=A0[2];
  }
  float wdv[4][3];
#pragma unroll
  for(int ctl=0;ctl<4;ctl++){
    int col=colBase+colOff+ctl*16+l15;
    if(col<mid){ wdv[ctl][0]=Wd[3*col]; wdv[ctl][1]=Wd[3*col+1]; wdv[ctl][2]=Wd[3*col+2]; }
    else { wdv[ctl][0]=0.f; wdv[ctl][1]=0.f; wdv[ctl][2]=0.f; }
  }
  f32x4 acc[4][4];
#pragma unroll
  for(int i=0;i<4;i++)
#pragma unroll
    for(int j=0;j<4;j++) acc[i][j]=(f32x4){0.f,0.f,0.f,0.f};
  int nct=cin>>5;
  int srow=tid>>1, shalf=tid&1;
  const int* idxB = idx + (size_t)rowBase*9;
  for(int k=0;k<9;k++){
    __syncthreads();
    if(tid<128){
      int p=idxB[tid*9+k]&nmask;
      idxS[tid]=p;
      const float* q=pB+(size_t)p*3;
      dispS[tid][0]=q[0]-ancS[tid][0];
      dispS[tid][1]=q[1]-ancS[tid][1];
      dispS[tid][2]=q[2]-ancS[tid][2];
      dispS[tid][3]=0.f;
    }
    f32x4 S[4][4];
#pragma unroll
    for(int i=0;i<4;i++)
#pragma unroll
      for(int j=0;j<4;j++) S[i][j]=(f32x4){0.f,0.f,0.f,0.f};
    for(int ct=0;ct<nct;ct++){
      __syncthreads();
      {
        int p=idxS[srow];
        const float* src=fB+(size_t)p*cin+(ct<<5)+(shalf<<4);
        float4 v0=((const float4*)src)[0];
        float4 v1=((const float4*)src)[1];
        float4 v2=((const float4*)src)[2];
        float4 v3=((const float4*)src)[3];
        f16x8 h0, h1;
        h0[0]=(f16)v0.x; h0[1]=(f16)v0.y; h0[2]=(f16)v0.z; h0[3]=(f16)v0.w;
        h0[4]=(f16)v1.x; h0[5]=(f16)v1.y; h0[6]=(f16)v1.z; h0[7]=(f16)v1.w;
        h1[0]=(f16)v2.x; h1[1]=(f16)v2.y; h1[2]=(f16)v2.z; h1[3]=(f16)v2.w;
        h1[4]=(f16)v3.x; h1[5]=(f16)v3.y; h1[6]=(f16)v3.z; h1[7]=(f16)v3.w;
        *(f16x8*)(As + srow*40 + (shalf<<4))     = h0;
        *(f16x8*)(As + srow*40 + (shalf<<4) + 8) = h1;
      }
      {
        const uint4* s=(const uint4*)(Wfh+(size_t)(colBase+srow)*cin+(ct<<5)+(shalf<<4));
        uint4 u0=s[0], u1=s[1];
        *(uint4*)(Bs + srow*40 + (shalf<<4))     = u0;
        *(uint4*)(Bs + srow*40 + (shalf<<4) + 8) = u1;
      }
      __syncthreads();
      f16x8 af[4], bf4[4];
#pragma unroll
      for(int rt=0;rt<4;rt++) af[rt]=*(const f16x8*)(As + (rowOff+rt*16+l15)*40 + quad*8);
#pragma unroll
      for(int ctl=0;ctl<4;ctl++) bf4[ctl]=*(const f16x8*)(Bs + (colOff+ctl*16+l15)*40 + quad*8);
#pragma unroll
      for(int rt=0;rt<4;rt++)
#pragma unroll
        for(int ctl=0;ctl<4;ctl++)
          S[rt][ctl]=__builtin_amdgcn_mfma_f32_16x16x32_f16(af[rt],bf4[ctl],S[rt][ctl],0,0,0);
    }
#pragma unroll
    for(int rt=0;rt<4;rt++){
#pragma unroll
      for(int r=0;r<4;r++){
        int rl=rowOff+rt*16+quad*4+r;
        float4 dv=*(const float4*)dispS[rl];
#pragma unroll
        for(int ctl=0;ctl<4;ctl++){
          float d=dv.x*wdv[ctl][0]+dv.y*wdv[ctl][1]+dv.z*wdv[ctl][2];
          acc[rt][ctl][r]+=S[rt][ctl][r]*d;
        }
      }
    }
  }
#pragma unroll
  for(int rt=0;rt<4;rt++){
#pragma unroll
    for(int r=0;r<4;r++){
      int row=rowBase+rowOff+rt*16+quad*4+r;
#pragma unroll
      for(int ctl=0;ctl<4;ctl++){
        int col=colBase+colOff+ctl*16+l15;
        if(col<mid) nf[(size_t)row*ld + jofs + col]=acc[rt][ctl][r];
      }
    }
  }
}

// ---------------------------------------------------------------- MFMA GEMM
template<bool RELU, bool DYN>
__global__ __launch_bounds__(256) void k_gemm_mfma(
    const float* __restrict__ Ag, const f16* __restrict__ Bh,
    const float* __restrict__ bias, void* __restrict__ out,
    int M, int K, int N, int mloc, size_t oBS, const int* __restrict__ oflag)
{
  __shared__ f16 As[128*40];
  __shared__ f16 Bs[128*40];
  int tid=threadIdx.x;
  int lane=tid&63, w=tid>>6;
  int quad=lane>>4, l15=lane&15;
  int rowOff=(w>>1)*64, colOff=(w&1)*64;
  int rowBase=blockIdx.x*128, colBase=blockIdx.y*128;
  f32x4 acc[4][4];
#pragma unroll
  for(int i=0;i<4;i++)
#pragma unroll
    for(int j=0;j<4;j++) acc[i][j]=(f32x4){0.f,0.f,0.f,0.f};
  int nct=K>>5;
  int srow=tid>>1, shalf=tid&1;
  for(int ct=0;ct<nct;ct++){
    __syncthreads();
    {
      const float* src=Ag+(size_t)(rowBase+srow)*K+(ct<<5)+(shalf<<4);
      float4 v0=((const float4*)src)[0];
      float4 v1=((const float4*)src)[1];
      float4 v2=((const float4*)src)[2];
      float4 v3=((const float4*)src)[3];
      f16x8 h0, h1;
      h0[0]=(f16)v0.x; h0[1]=(f16)v0.y; h0[2]=(f16)v0.z; h0[3]=(f16)v0.w;
      h0[4]=(f16)v1.x; h0[5]=(f16)v1.y; h0[6]=(f16)v1.z; h0[7]=(f16)v1.w;
      h1[0]=(f16)v2.x; h1[1]=(f16)v2.y; h1[2]=(f16)v2.z; h1[3]=(f16)v2.w;
      h1[4]=(f16)v3.x; h1[5]=(f16)v3.y; h1[6]=(f16)v3.z; h1[7]=(f16)v3.w;
      *(f16x8*)(As + srow*40 + (shalf<<4))     = h0;
      *(f16x8*)(As + srow*40 + (shalf<<4) + 8) = h1;
    }
    {
      const uint4* s=(const uint4*)(Bh+(size_t)(colBase+srow)*K+(ct<<5)+(shalf<<4));
      uint4 u0=s[0], u1=s[1];
      *(uint4*)(Bs + srow*40 + (shalf<<4))     = u0;
      *(uint4*)(Bs + srow*40 + (shalf<<4) + 8) = u1;
    }
    __syncthreads();
    f16x8 af[4], bf4[4];
#pragma unroll
    for(int rt=0;rt<4;rt++) af[rt]=*(const f16x8*)(As + (rowOff+rt*16+l15)*40 + quad*8);
#pragma unroll
    for(int ctl=0;ctl<4;ctl++) bf4[ctl]=*(const f16x8*)(Bs + (colOff+ctl*16+l15)*40 + quad*8);
#pragma unroll
    for(int rt=0;rt<4;rt++)
#pragma unroll
      for(int ctl=0;ctl<4;ctl++)
        acc[rt][ctl]=__builtin_amdgcn_mfma_f32_16x16x32_f16(af[rt],bf4[ctl],acc[rt][ctl],0,0,0);
  }
  bool f32m = DYN ? (*oflag!=0) : true;
#pragma unroll
  for(int rt=0;rt<4;rt++){
#pragma unroll
    for(int r=0;r<4;r++){
      int row=rowBase+rowOff+rt*16+quad*4+r;
      int rb=row/mloc, rm=row-rb*mloc;
      size_t obase=(size_t)rb*oBS + (size_t)rm*N;
#pragma unroll
      for(int ctl=0;ctl<4;ctl++){
        int col=colBase+colOff+ctl*16+l15;
        float v=acc[rt][ctl][r];
        if(bias) v+=bias[col];
        if(RELU) v=fmaxf(v,0.f);
        if(DYN && !f32m) ((bf16*)out)[obase+col]=__float2bfloat16(v);
        else             ((float*)out)[obase+col]=v;
      }
    }
  }
}

// ---------------------------------------------------------------- BatchNorm
__global__ void k_bnstat(const float* __restrict__ nf, int M, int C, float* __restrict__ sums){
  int c = blockIdx.x*256 + threadIdx.x;
  if(c>=C) return;
  int rows = M>>5;
  int r0 = blockIdx.y*rows, r1 = r0+rows;
  float s=0.f, s2=0.f;
  for(int r=r0;r<r1;r++){
    float v=nf[(size_t)r*C+c];
    s+=v; s2+=v*v;
  }
  atomicAdd(&sums[c], s);
  atomicAdd(&sums[C+c], s2);
}

__global__ void k_bnapply(float* __restrict__ nf, const float* __restrict__ sums, int M, int C){
  long long i = (long long)blockIdx.x*256 + threadIdx.x;
  long long tot = (long long)M*C;
  if(i>=tot) return;
  int c = (int)(i % (long long)C);
  float mean = sums[c]/(float)M;
  float var = sums[C+c]/(float)M - mean*mean;
  if(var<0.f) var=0.f;
  float v = (nf[i]-mean)/sqrtf(var+1e-5f);
  nf[i] = v>0.f? v:0.f;
}

// ---------------------------------------------------------------- f32 GEMM (layer 0 temporal, K=45)
template<int TN, bool ALIGNED, bool RELU>
__global__ __launch_bounds__(256) void k_gemm(
    const float* __restrict__ Ag, const float* __restrict__ Wg,
    const float* __restrict__ bias, float* __restrict__ out,
    int M, int K, int N, int mloc, size_t oBS)
{
  constexpr int CW = TN/16;
  __shared__ alignas(16) float As[16][64];
  __shared__ alignas(16) float Bs[16][TN];
  int tid=threadIdx.x, tx=tid&15, ty=tid>>4;
  int rowBase=blockIdx.x*64, colBase=blockIdx.y*TN;
  float acc[4][CW];
#pragma unroll
  for(int i=0;i<4;i++)
#pragma unroll
    for(int j=0;j<CW;j++) acc[i][j]=0.f;
  int lrow=tid&63, lcq=tid>>6;
  int nct=(K+15)>>4;
  for(int ct=0;ct<nct;ct++){
    __syncthreads();
    {
      int r=rowBase+lrow, c0=(ct<<4)+(lcq<<2);
#pragma unroll
      for(int q=0;q<4;q++){
        int c=c0+q;
        As[(lcq<<2)+q][lrow] = (ALIGNED||c<K)? Ag[(size_t)r*K+c] : 0.f;
      }
    }
    {
      int og=colBase+lrow, c0=(ct<<4)+(lcq<<2);
#pragma unroll
      for(int q=0;q<4;q++){
        int c=c0+q;
        Bs[(lcq<<2)+q][lrow] = (ALIGNED||c<K)? Wg[(size_t)og*K+c] : 0.f;
      }
    }
    __syncthreads();
#pragma unroll
    for(int c=0;c<16;c++){
      float4 a4=*(const float4*)&As[c][ty<<2];
      float av[4]={a4.x,a4.y,a4.z,a4.w};
      float bw[CW];
#pragma unroll
      for(int j0=0;j0<CW;j0+=4){
        float4 b4=*(const float4*)&Bs[c][tx*CW+j0];
        bw[j0]=b4.x; bw[j0+1]=b4.y; bw[j0+2]=b4.z; bw[j0+3]=b4.w;
      }
#pragma unroll
      for(int i=0;i<4;i++)
#pragma unroll
        for(int j=0;j<CW;j++) acc[i][j]+=av[i]*bw[j];
    }
  }
#pragma unroll
  for(int i=0;i<4;i++){
    int r=rowBase+(ty<<2)+i;
    int rb=r/mloc, rm=r-rb*mloc;
    size_t obase=(size_t)rb*oBS + (size_t)rm*N;
#pragma unroll
    for(int j=0;j<CW;j++){
      int o=colBase+tx*CW+j;
      float v=acc[i][j];
      if(bias) v+=bias[o];
      if(RELU) v=fmaxf(v,0.f);
      out[obase+o]=v;
    }
  }
}

// ---------------------------------------------------------------- host
extern "C" void kernel_launch(void* const* d_in, const int* in_sizes, int n_in,
                              void* d_out, int out_size, void* d_ws, size_t ws_size,
                              hipStream_t stream) {
  (void)in_sizes; (void)n_in; (void)out_size; (void)ws_size;

  const int di[6] = {2,4,7,10,13,16};
  const int fi[6] = {-1,5,8,11,14,17};
  const int ti[6] = {3,6,9,12,15,18};

  const int midv[6]={45,96,192,384,768,1536};
  const int midp[6]={0,128,256,384,768,1536};
  const int cinv[6]={0,64,128,256,512,1024};
  const int coutv[6]={64,128,256,512,1024,2048};
  const int tkv[6]={1,3,3,3,3,1};
  const int Nv[6]={2048,1024,512,512,256,256};
  const int mv[6]={1024,512,512,256,256,128};
  const int Lv[6]={4,4,2,2,1,1};
  const int Tv[6]={4,2,2,1,1,1};
  const float rrv[6]={1.5f,3.f,3.f,6.f,6.f,6.f};

  float* ws=(float*)d_ws;
  size_t off=0;
  auto A=[&](size_t n)->float*{ float* p=ws+off; off+=(n+63)&~(size_t)63; return p; };
  auto Ah=[&](size_t n)->f16*{ return (f16*)A((n+1)/2); };

  int* flag=(int*)A(64);

  float *Wd[6]; f16 *Wfh[6], *Wth[6];
  float* Wt0;
  for(int l=0;l<6;l++){
    Wd[l]=A((size_t)midv[l]*3);
    Wfh[l]= cinv[l]? Ah((size_t)midp[l]*cinv[l]) : nullptr;
    Wth[l]= l? Ah((size_t)coutv[l]*tkv[l]*midv[l]) : nullptr;
  }
  Wt0=A((size_t)64*45);
  f16* fcwh=Ah(1024ull*2048);
  float* fcb=A(1024);

  float* X[7];
  X[0]=A(32ull*4*2048*3);
  for(int l=0;l<6;l++) X[l+1]=A((size_t)32*Tv[l]*mv[l]*3);

  float* FA=A(8388608);
  float* FB=A(8388608);
  float* F[7]; F[0]=nullptr;
  for(int l=0;l<6;l++) F[l+1]=(l%2==0)?FA:FB;

  float* nf=A(18874368);
  float* sums=A(4608);
  int* bq=(int*)A(32ull*1024*9);

  k_detect<<<dim3(1),dim3(256),0,stream>>>((const unsigned int*)d_in[0], 4096, flag);

  auto cvt=[&](const void* s, float* d, size_t n){
    k_cvt<<<dim3((unsigned)((n+255)/256)),dim3(256),0,stream>>>(s,d,(int)n,flag);
  };
  auto cvth=[&](const void* s, f16* d, size_t nsrc, size_t npad){
    k_cvth<<<dim3((unsigned)((npad+255)/256)),dim3(256),0,stream>>>(s,d,(int)nsrc,(int)npad,flag);
  };
  cvt(d_in[0], X[0], 32ull*4*2048*3);
  for(int l=0;l<6;l++){
    cvt(d_in[di[l]], Wd[l], (size_t)midv[l]*3);
    if(cinv[l]) cvth(d_in[fi[l]], Wfh[l], (size_t)midv[l]*cinv[l], (size_t)midp[l]*cinv[l]);
    if(l) cvth(d_in[ti[l]], Wth[l], (size_t)coutv[l]*tkv[l]*midv[l], (size_t)coutv[l]*tkv[l]*midv[l]);
  }
  cvt(d_in[3], Wt0, 64*45);
  cvth(d_in[19], fcwh, 1024ull*2048, 1024ull*2048);
  cvt(d_in[20], fcb, 1024);

  struct PairT{int j,i;};
  const int Tcenters[6][4]={{0,1,2,3},{0,2,0,0},{0,1,0,0},{0,0,0,0},{0,0,0,0},{0,0,0,0}};
  const int npairs[6][4]={{1,1,1,1},{2,3,0,0},{2,2,0,0},{2,0,0,0},{1,0,0,0},{1,0,0,0}};
  const PairT pr[6][4][3]={
    { {{0,0},{0,0},{0,0}}, {{0,1},{0,0},{0,0}}, {{0,2},{0,0},{0,0}}, {{0,3},{0,0},{0,0}} },
    { {{1,0},{2,1},{0,0}}, {{0,1},{1,2},{2,3}}, {{0,0},{0,0},{0,0}}, {{0,0},{0,0},{0,0}} },
    { {{1,0},{2,1},{0,0}}, {{0,0},{1,1},{0,0}}, {{0,0},{0,0},{0,0}}, {{0,0},{0,0},{0,0}} },
    { {{1,0},{2,1},{0,0}}, {{0,0},{0,0},{0,0}}, {{0,0},{0,0},{0,0}}, {{0,0},{0,0},{0,0}} },
    { {{1,0},{0,0},{0,0}}, {{0,0},{0,0},{0,0}}, {{0,0},{0,0},{0,0}}, {{0,0},{0,0},{0,0}} },
    { {{0,0},{0,0},{0,0}}, {{0,0},{0,0},{0,0}}, {{0,0},{0,0},{0,0}}, {{0,0},{0,0},{0,0}} },
  };

  for(int l=0;l<6;l++){
    int N=Nv[l], m=mv[l], Lin=Lv[l], T=Tv[l], cin=cinv[l], mid=midv[l];
    int C=tkv[l]*midv[l], M=32*m, cout=coutv[l];
    float r2=rrv[l]*rrv[l];
    const float* Xin=X[l]; float* Xout=X[l+1];

    {
      dim3 g(32*T), blk(256);
      int a0=Tcenters[l][0],a1=Tcenters[l][1],a2=Tcenters[l][2],a3=Tcenters[l][3];
      if(N==2048)      k_fps2<8><<<g,blk,0,stream>>>(Xin,Lin,N,m,a0,a1,a2,a3,T,Xout);
      else if(N==1024) k_fps2<4><<<g,blk,0,stream>>>(Xin,Lin,N,m,a0,a1,a2,a3,T,Xout);
      else if(N==512)  k_fps2<2><<<g,blk,0,stream>>>(Xin,Lin,N,m,a0,a1,a2,a3,T,Xout);
      else             k_fps2<1><<<g,blk,0,stream>>>(Xin,Lin,N,m,a0,a1,a2,a3,T,Xout);
    }

    for(int tt=0; tt<T; ++tt){
      k_zero<<<dim3((unsigned)(((size_t)M*C+255)/256)),256,0,stream>>>(nf,(int)((size_t)M*C));
      k_zero<<<dim3((unsigned)((2*C+255)/256)),256,0,stream>>>(sums,2*C);
      const float* anc = Xout + (size_t)tt*m*3;
      size_t aBS=(size_t)T*m*3;
      for(int pi=0; pi<npairs[l][tt]; ++pi){
        int j=pr[l][tt][pi].j, i=pr[l][tt][pi].i;
        const float* pts = Xin + (size_t)i*N*3;
        size_t pBS=(size_t)Lin*N*3;
        int chunks=(m+255)>>8;
        k_bq<<<dim3(32*chunks),256,0,stream>>>(pts,anc,bq,N,m,r2,pBS,aBS);
        if(l==0){
          k_part0<<<dim3(M),64,0,stream>>>(pts,anc,bq,Wd[0],nf,m,mid,C,N-1,pBS,aBS);
        } else {
          const float* fin = F[l] + (size_t)i*N*cin;
          size_t fBS=(size_t)Lin*N*cin;
          k_pair_mfma<<<dim3(M/128, midp[l]/128),256,0,stream>>>(
              fin,pts,anc,bq,Wfh[l],Wd[l],nf,m,cin,mid,C,j*mid,N-1,fBS,pBS,aBS);
        }
      }
      k_bnstat<<<dim3((C+255)/256,32),256,0,stream>>>(nf,M,C,sums);
      k_bnapply<<<dim3((unsigned)(((size_t)M*C+255)/256)),256,0,stream>>>(nf,sums,M,C);
      float* outp = F[l+1] + (size_t)tt*m*cout;
      size_t oBS=(size_t)T*m*cout;
      if(l==0)
        k_gemm<64,false,true><<<dim3(M/64,cout/64),256,0,stream>>>(nf,Wt0,nullptr,outp,M,C,cout,m,oBS);
      else if(l<5)
        k_gemm_mfma<true,false><<<dim3(M/128,cout/128),256,0,stream>>>(nf,Wth[l],nullptr,outp,M,C,cout,m,oBS,nullptr);
      else
        k_gemm_mfma<false,false><<<dim3(M/128,cout/128),256,0,stream>>>(nf,Wth[l],nullptr,outp,M,C,cout,m,oBS,nullptr);
    }
  }

  k_gemm_mfma<false,true><<<dim3(4096/128,1024/128),256,0,stream>>>(
      F[6],fcwh,fcb,d_out,4096,2048,1024,128,(size_t)128*1024,flag);
}

// Round 6
// 5410.128 us; speedup vs baseline: 1.4181x; 1.1185x over previous
//
#include <hip/hip_runtime.h>
#include <hip/hip_bf16.h>
#include <math.h>

typedef __hip_bfloat16 bf16;
typedef _Float16 f16;
typedef _Float16 f16x8 __attribute__((ext_vector_type(8)));
typedef float f32x4 __attribute__((ext_vector_type(4)));

struct Pairs { int i[3]; int j[3]; };
struct CvtF32 { const void* src[4]; float* dst[4]; int n[4]; int blk0[5]; };
struct CvtF16 { const void* src[6]; f16* dst[6]; int n[6]; int blk0[7]; };

// ---------------------------------------------------------------- dtype detect
__global__ void k_detect(const unsigned int* __restrict__ w, int nwords, int* __restrict__ flag){
  __shared__ int cnt;
  if(threadIdx.x==0) cnt=0;
  __syncthreads();
  int local=0;
  for(int i=threadIdx.x;i<nwords;i+=256){
    unsigned int v=w[i];
    int e=(v>>7)&0xFF;
    if(e>=0xC0) local++;
  }
  atomicAdd(&cnt, local);
  __syncthreads();
  if(threadIdx.x==0) flag[0] = (cnt > (nwords>>3)) ? 1 : 0;
}

__device__ inline float ldmix(const void* p, size_t i, bool f32m){
  return f32m ? ((const float*)p)[i] : __bfloat162float(((const bf16*)p)[i]);
}

// ---------------------------------------------------------------- fused converts
__global__ void k_cvt_all(CvtF32 J, const int* __restrict__ flag){
  int b=blockIdx.x;
  int j=0;
  while(j<3 && J.blk0[j+1]<=b) j++;
  int i=(b-J.blk0[j])*256+threadIdx.x;
  if(i>=J.n[j]) return;
  bool f32m=*flag!=0;
  J.dst[j][i]=ldmix(J.src[j],i,f32m);
}

__global__ void k_cvth_all(CvtF16 J, const int* __restrict__ flag){
  int b=blockIdx.x;
  int j=0;
  while(j<5 && J.blk0[j+1]<=b) j++;
  int i=(b-J.blk0[j])*256+threadIdx.x;
  if(i>=J.n[j]) return;
  bool f32m=*flag!=0;
  J.dst[j][i]=(f16)ldmix(J.src[j],i,f32m);
}

__global__ void k_zero(float* __restrict__ p, int n){
  int i = blockIdx.x*256 + threadIdx.x;
  if(i<n) p[i]=0.f;
}

// ---------------------------------------------------------------- W2[o, a*cin+c] = Wd[o,a]*Wf[o,c]
__global__ void k_w2(const void* __restrict__ WdS, const void* __restrict__ WfS,
                     f16* __restrict__ W2, int mid, int cin, int tot, const int* __restrict__ flag){
  int i=blockIdx.x*256+threadIdx.x;
  if(i>=tot) return;
  int K3=3*cin;
  int o=i/K3; int rem=i-o*K3; int a=rem/cin; int c=rem-a*cin;
  float v=0.f;
  if(o<mid){
    bool f32m=*flag!=0;
    float wd=ldmix(WdS,(size_t)3*o+a,f32m);
    float wf=ldmix(WfS,(size_t)o*cin+c,f32m);
    v=wd*wf;
  }
  W2[i]=(f16)v;
}

// ---------------------------------------------------------------- FPS: 1 wave, DPP argmax, no barriers
template<int P>
__global__ __launch_bounds__(64) void k_fps3(
    const float* __restrict__ xyz, int L, int N, int m,
    int c0,int c1,int c2,int c3, int T, float* __restrict__ anchors)
{
  __shared__ float4 ptsS[64*P];
  int prob=blockIdx.x;
  int b=prob/T, tt=prob%T;
  int f=(tt==0)?c0:(tt==1)?c1:(tt==2)?c2:c3;
  const float* src = xyz + ((size_t)(b*L+f))*N*3;
  float* anc = anchors + ((size_t)(b*T+tt))*m*3;
  int lane=threadIdx.x;
  for(int t=lane;t<N;t+=64)
    ptsS[t]=make_float4(src[3*t],src[3*t+1],src[3*t+2],0.f);
  __syncthreads();
  float px[P],py[P],pz[P],mind[P];
#pragma unroll
  for(int j=0;j<P;j++){
    float4 v=ptsS[lane+j*64];
    px[j]=v.x; py[j]=v.y; pz[j]=v.z; mind[j]=1e10f;
  }
  float4 p0=ptsS[0];
  float lx=p0.x, ly=p0.y, lz=p0.z;
  if(lane==0){ anc[0]=lx; anc[1]=ly; anc[2]=lz; }
  for(int it=1; it<m; ++it){
    float bv=-1.f; int bi=0;
#pragma unroll
    for(int j=0;j<P;j++){
#pragma clang fp contract(off)
      float dx=px[j]-lx, dy=py[j]-ly, dz=pz[j]-lz;
      float d2=dx*dx+dy*dy+dz*dz;
      float mv=mind[j]; if(d2<mv) mv=d2; mind[j]=mv;
      if(mv>bv){ bv=mv; bi=lane+j*64; }
    }
    unsigned int hi=__float_as_uint(bv);           // dist>=0: IEEE order == uint order
    unsigned int lo=0xFFFFFFFFu-(unsigned)bi;      // bigger lo == smaller index (tie->first)
#define DPPSTEP(CTRL) { \
    unsigned int shi=(unsigned)__builtin_amdgcn_update_dpp(0,(int)hi,CTRL,0xF,0xF,true); \
    unsigned int slo=(unsigned)__builtin_amdgcn_update_dpp(0,(int)lo,CTRL,0xF,0xF,true); \
    bool g=(shi>hi)||(shi==hi&&slo>lo); \
    hi=g?shi:hi; lo=g?slo:lo; }
    DPPSTEP(0x111) DPPSTEP(0x112) DPPSTEP(0x114) DPPSTEP(0x118) DPPSTEP(0x142) DPPSTEP(0x143)
#undef DPPSTEP
    unsigned int low=(unsigned)__builtin_amdgcn_readlane((int)lo,63);
    int wi=(int)(0xFFFFFFFFu-low);
    float4 wc=ptsS[wi];
    lx=wc.x; ly=wc.y; lz=wc.z;
    if(lane==0){ anc[3*it]=lx; anc[3*it+1]=ly; anc[3*it+2]=lz; }
  }
}

// ---------------------------------------------------------------- ball query (batched over pairs, exact f32)
__global__ __launch_bounds__(256) void k_bq(
    const float* __restrict__ Xin, const float* __restrict__ anc,
    int* __restrict__ outAll, int N, int m, float r2, int Lin, size_t aBS, Pairs P)
{
  int chunks=(m+255)>>8;
  int b=blockIdx.x/chunks;
  int a=(blockIdx.x%chunks)*256+threadIdx.x;
  int gy=blockIdx.y;
  const float* Pb = Xin + ((size_t)b*Lin + P.i[gy])*(size_t)N*3;
  bool act = a<m;
  float ax=0,ay=0,az=0;
  int* o = outAll + ((size_t)gy*32*m + (size_t)b*m + (size_t)(act?a:0))*9;
  if(act){ const float* A=anc+(size_t)b*aBS+(size_t)a*3; ax=A[0]; ay=A[1]; az=A[2]; }
  int cnt = act?0:9, first=0;
  __shared__ float sp[768];
  for(int base=0; base<N; base+=256){
    for(int t=threadIdx.x; t<768; t+=256) sp[t]=Pb[(size_t)base*3+t];
    __syncthreads();
    for(int q=0;q<256;q++){
#pragma clang fp contract(off)
      float dx=sp[3*q]-ax, dy=sp[3*q+1]-ay, dz=sp[3*q+2]-az;
      float d2=dx*dx+dy*dy+dz*dz;
      if(d2<r2 && cnt<9){
        int p=base+q;
        if(cnt==0) first=p;
        o[cnt]=p; cnt++;
      }
    }
    if(__syncthreads_and(cnt>=9)) break;
  }
  if(act){ for(int k=cnt;k<9;k++) o[k]=first; }
}

// ---------------------------------------------------------------- layer 0 (cin=0): nf = sum_k disp_k . Wd
__global__ void k_part0(
    const float* __restrict__ pts, const float* __restrict__ anc,
    const int* __restrict__ idx, const float* __restrict__ Wd,
    float* __restrict__ nf, int m, int mid, int ld, int nmask,
    size_t pBS, size_t aBS)
{
  int row = blockIdx.x;
  int b = row/m, mm = row - b*m;
  int o = threadIdx.x;
  const float* A = anc + (size_t)b*aBS + (size_t)mm*3;
  float ax=A[0], ay=A[1], az=A[2];
  float w0=0,w1=0,w2=0;
  if(o<mid){ w0=Wd[3*o]; w1=Wd[3*o+1]; w2=Wd[3*o+2]; }
  const int* id = idx + (size_t)row*9;
  const float* Pb = pts + (size_t)b*pBS;
  float acc=0.f;
  for(int k=0;k<9;k++){
    int p=id[k] & nmask;
    const float* q = Pb + (size_t)p*3;
    float dx=q[0]-ax, dy=q[1]-ay, dz=q[2]-az;
    acc += dx*w0+dy*w1+dz*w2;
  }
  if(o<mid) nf[(size_t)row*ld + o] = acc;
}

// ---------------------------------------------------------------- G[m, a*cin+c] = sum_k disp[m,k,a]*fg[m,k,c]
__global__ __launch_bounds__(256) void k_outer(
    const float* __restrict__ feats, const float* __restrict__ Xin,
    const float* __restrict__ anc, const int* __restrict__ bqAll,
    f16* __restrict__ Gh, int m, int cin, int N, int Lin, size_t aBS, int nmask, Pairs P)
{
  int M=32*m;
  int cw = cin<256? cin:256;
  int rpb = 256/cw;
  int tid=threadIdx.x;
  int sub=tid/cw, lc=tid-sub*cw;
  int r=blockIdx.x*rpb+sub;
  int Kp=3*cin;
  int pi=r/M, mrow=r-pi*M;
  int b=mrow/m, mm=mrow-b*m;
  const float* A0=anc+(size_t)b*aBS+(size_t)mm*3;
  float ax=A0[0],ay=A0[1],az=A0[2];
  int fr=P.i[pi];
  const float* Pb=Xin+((size_t)b*Lin+fr)*(size_t)N*3;
  const float* Fb=feats+(((size_t)b*Lin+fr)*(size_t)N)*cin;
  const int* id=bqAll+(size_t)r*9;
  int idx[9]; float d0[9],d1[9],d2a[9];
#pragma unroll
  for(int k=0;k<9;k++){
    int p=id[k]&nmask; idx[k]=p;
    const float* q=Pb+(size_t)p*3;
    d0[k]=q[0]-ax; d1[k]=q[1]-ay; d2a[k]=q[2]-az;
  }
  f16* Gr=Gh+(size_t)r*Kp;
  for(int cc=lc; cc<cin; cc+=cw){
    float a0=0.f,a1=0.f,a2=0.f;
#pragma unroll
    for(int k=0;k<9;k++){
      float fv=Fb[(size_t)idx[k]*cin+cc];
      a0=fmaf(d0[k],fv,a0); a1=fmaf(d1[k],fv,a1); a2=fmaf(d2a[k],fv,a2);
    }
    Gr[cc]=(f16)a0; Gr[cin+cc]=(f16)a1; Gr[2*cin+cc]=(f16)a2;
  }
}

// ---------------------------------------------------------------- pair GEMM: nf[mrow, j*mid+col] = G @ W2^T
__global__ __launch_bounds__(256) void k_pg(
    const f16* __restrict__ Gh, const f16* __restrict__ W2,
    float* __restrict__ nf, int Kp, int mid, int C, int M, Pairs P)
{
  __shared__ f16 As[128*40];
  __shared__ f16 Bs[128*40];
  int tid=threadIdx.x;
  int lane=tid&63, w=tid>>6;
  int quad=lane>>4, l15=lane&15;
  int rowOff=(w>>1)*64, colOff=(w&1)*64;
  int rowBase=blockIdx.x*128, colBase=blockIdx.y*128;
  f32x4 acc[4][4];
#pragma unroll
  for(int i=0;i<4;i++)
#pragma unroll
    for(int j=0;j<4;j++) acc[i][j]=(f32x4){0.f,0.f,0.f,0.f};
  int nct=Kp>>5;
  int srow=tid>>1, shalf=tid&1;
  for(int ct=0;ct<nct;ct++){
    __syncthreads();
    {
      const uint4* s=(const uint4*)(Gh+(size_t)(rowBase+srow)*Kp+(ct<<5)+(shalf<<4));
      uint4 u0=s[0], u1=s[1];
      *(uint4*)(As + srow*40 + (shalf<<4))     = u0;
      *(uint4*)(As + srow*40 + (shalf<<4) + 8) = u1;
    }
    {
      const uint4* s=(const uint4*)(W2+(size_t)(colBase+srow)*Kp+(ct<<5)+(shalf<<4));
      uint4 u0=s[0], u1=s[1];
      *(uint4*)(Bs + srow*40 + (shalf<<4))     = u0;
      *(uint4*)(Bs + srow*40 + (shalf<<4) + 8) = u1;
    }
    __syncthreads();
    f16x8 af[4], bf4[4];
#pragma unroll
    for(int rt=0;rt<4;rt++) af[rt]=*(const f16x8*)(As + (rowOff+rt*16+l15)*40 + quad*8);
#pragma unroll
    for(int ctl=0;ctl<4;ctl++) bf4[ctl]=*(const f16x8*)(Bs + (colOff+ctl*16+l15)*40 + quad*8);
#pragma unroll
    for(int rt=0;rt<4;rt++)
#pragma unroll
      for(int ctl=0;ctl<4;ctl++)
        acc[rt][ctl]=__builtin_amdgcn_mfma_f32_16x16x32_f16(af[rt],bf4[ctl],acc[rt][ctl],0,0,0);
  }
#pragma unroll
  for(int rt=0;rt<4;rt++){
#pragma unroll
    for(int r=0;r<4;r++){
      int row=rowBase+rowOff+rt*16+quad*4+r;
      int pi=row/M, mrow=row-pi*M;
      int j=P.j[pi];
#pragma unroll
      for(int ctl=0;ctl<4;ctl++){
        int col=colBase+colOff+ctl*16+l15;
        if(col<mid) nf[(size_t)mrow*C + j*mid + col]=acc[rt][ctl][r];
      }
    }
  }
}

// ---------------------------------------------------------------- BN stats (jmask: skip never-written slices)
__global__ void k_bnstat(const float* __restrict__ nf, int M, int C, float* __restrict__ sums,
                         int mid, int jmask){
  int c = blockIdx.x*256 + threadIdx.x;
  if(c>=C) return;
  int j=c/mid;
  if(!((jmask>>j)&1)) return;
  int rows = M>>5;
  int r0 = blockIdx.y*rows, r1 = r0+rows;
  float s=0.f, s2=0.f;
  for(int r=r0;r<r1;r++){
    float v=nf[(size_t)r*C+c];
    s+=v; s2+=v*v;
  }
  atomicAdd(&sums[c], s);
  atomicAdd(&sums[C+c], s2);
}

// per-col scale/bias; invalid cols -> 0 (annihilates garbage)
__global__ void k_bnfin(const float* __restrict__ sums, float* __restrict__ scb,
                        int C, int M, int mid, int jmask){
  int c = blockIdx.x*256 + threadIdx.x;
  if(c>=C) return;
  int j=c/mid;
  if(!((jmask>>j)&1)){ scb[c]=0.f; scb[C+c]=0.f; return; }
  float mean=sums[c]/(float)M;
  float var=sums[C+c]/(float)M - mean*mean;
  if(var<0.f) var=0.f;
  float rs=1.0f/sqrtf(var+1e-5f);
  scb[c]=rs; scb[C+c]=-mean*rs;
}

// ---------------------------------------------------------------- MFMA GEMM (A f32, opt fused BN+ReLU on A)
__device__ inline float4 bnr(float4 v, float4 s, float4 b){
  float4 r;
  r.x=fmaxf(fmaf(v.x,s.x,b.x),0.f); r.y=fmaxf(fmaf(v.y,s.y,b.y),0.f);
  r.z=fmaxf(fmaf(v.z,s.z,b.z),0.f); r.w=fmaxf(fmaf(v.w,s.w,b.w),0.f);
  return r;
}

template<bool RELU, bool DYN, bool BNA>
__global__ __launch_bounds__(256) void k_gemm_mfma(
    const float* __restrict__ Ag, const f16* __restrict__ Bh,
    const float* __restrict__ bias, void* __restrict__ out,
    int M, int K, int N, int mloc, size_t oBS, const int* __restrict__ oflag,
    const float* __restrict__ scb)
{
  __shared__ f16 As[128*40];
  __shared__ f16 Bs[128*40];
  int tid=threadIdx.x;
  int lane=tid&63, w=tid>>6;
  int quad=lane>>4, l15=lane&15;
  int rowOff=(w>>1)*64, colOff=(w&1)*64;
  int rowBase=blockIdx.x*128, colBase=blockIdx.y*128;
  f32x4 acc[4][4];
#pragma unroll
  for(int i=0;i<4;i++)
#pragma unroll
    for(int j=0;j<4;j++) acc[i][j]=(f32x4){0.f,0.f,0.f,0.f};
  int nct=K>>5;
  int srow=tid>>1, shalf=tid&1;
  for(int ct=0;ct<nct;ct++){
    __syncthreads();
    {
      int c0g=(ct<<5)+(shalf<<4);
      const float* src=Ag+(size_t)(rowBase+srow)*K+c0g;
      float4 v0=((const float4*)src)[0];
      float4 v1=((const float4*)src)[1];
      float4 v2=((const float4*)src)[2];
      float4 v3=((const float4*)src)[3];
      if(BNA){
        const float* sc=scb+c0g;
        const float* bi=scb+K+c0g;
        float4 s0=((const float4*)sc)[0], s1=((const float4*)sc)[1],
               s2=((const float4*)sc)[2], s3=((const float4*)sc)[3];
        float4 b0=((const float4*)bi)[0], b1=((const float4*)bi)[1],
               b2=((const float4*)bi)[2], b3=((const float4*)bi)[3];
        v0=bnr(v0,s0,b0); v1=bnr(v1,s1,b1); v2=bnr(v2,s2,b2); v3=bnr(v3,s3,b3);
      }
      f16x8 h0, h1;
      h0[0]=(f16)v0.x; h0[1]=(f16)v0.y; h0[2]=(f16)v0.z; h0[3]=(f16)v0.w;
      h0[4]=(f16)v1.x; h0[5]=(f16)v1.y; h0[6]=(f16)v1.z; h0[7]=(f16)v1.w;
      h1[0]=(f16)v2.x; h1[1]=(f16)v2.y; h1[2]=(f16)v2.z; h1[3]=(f16)v2.w;
      h1[4]=(f16)v3.x; h1[5]=(f16)v3.y; h1[6]=(f16)v3.z; h1[7]=(f16)v3.w;
      *(f16x8*)(As + srow*40 + (shalf<<4))     = h0;
      *(f16x8*)(As + srow*40 + (shalf<<4) + 8) = h1;
    }
    {
      const uint4* s=(const uint4*)(Bh+(size_t)(colBase+srow)*K+(ct<<5)+(shalf<<4));
      uint4 u0=s[0], u1=s[1];
      *(uint4*)(Bs + srow*40 + (shalf<<4))     = u0;
      *(uint4*)(Bs + srow*40 + (shalf<<4) + 8) = u1;
    }
    __syncthreads();
    f16x8 af[4], bf4[4];
#pragma unroll
    for(int rt=0;rt<4;rt++) af[rt]=*(const f16x8*)(As + (rowOff+rt*16+l15)*40 + quad*8);
#pragma unroll
    for(int ctl=0;ctl<4;ctl++) bf4[ctl]=*(const f16x8*)(Bs + (colOff+ctl*16+l15)*40 + quad*8);
#pragma unroll
    for(int rt=0;rt<4;rt++)
#pragma unroll
      for(int ctl=0;ctl<4;ctl++)
        acc[rt][ctl]=__builtin_amdgcn_mfma_f32_16x16x32_f16(af[rt],bf4[ctl],acc[rt][ctl],0,0,0);
  }
  bool f32m = DYN ? (*oflag!=0) : true;
#pragma unroll
  for(int rt=0;rt<4;rt++){
#pragma unroll
    for(int r=0;r<4;r++){
      int row=rowBase+rowOff+rt*16+quad*4+r;
      int rb=row/mloc, rm=row-rb*mloc;
      size_t obase=(size_t)rb*oBS + (size_t)rm*N;
#pragma unroll
      for(int ctl=0;ctl<4;ctl++){
        int col=colBase+colOff+ctl*16+l15;
        float v=acc[rt][ctl][r];
        if(bias) v+=bias[col];
        if(RELU) v=fmaxf(v,0.f);
        if(DYN && !f32m) ((bf16*)out)[obase+col]=__float2bfloat16(v);
        else             ((float*)out)[obase+col]=v;
      }
    }
  }
}

// ---------------------------------------------------------------- f32 GEMM (layer 0, K=45) with fused BN+ReLU
template<int TN, bool RELU>
__global__ __launch_bounds__(256) void k_gemm(
    const float* __restrict__ Ag, const float* __restrict__ Wg,
    float* __restrict__ out, int M, int K, int N, int mloc, size_t oBS,
    const float* __restrict__ scb)
{
  constexpr int CW = TN/16;
  __shared__ alignas(16) float As[16][64];
  __shared__ alignas(16) float Bs[16][TN];
  int tid=threadIdx.x, tx=tid&15, ty=tid>>4;
  int rowBase=blockIdx.x*64, colBase=blockIdx.y*TN;
  float acc[4][CW];
#pragma unroll
  for(int i=0;i<4;i++)
#pragma unroll
    for(int j=0;j<CW;j++) acc[i][j]=0.f;
  int lrow=tid&63, lcq=tid>>6;
  int nct=(K+15)>>4;
  for(int ct=0;ct<nct;ct++){
    __syncthreads();
    {
      int r=rowBase+lrow, c0=(ct<<4)+(lcq<<2);
#pragma unroll
      for(int q=0;q<4;q++){
        int c=c0+q;
        As[(lcq<<2)+q][lrow] = (c<K)? fmaxf(fmaf(Ag[(size_t)r*K+c],scb[c],scb[K+c]),0.f) : 0.f;
      }
    }
    {
      int og=colBase+lrow, c0=(ct<<4)+(lcq<<2);
#pragma unroll
      for(int q=0;q<4;q++){
        int c=c0+q;
        Bs[(lcq<<2)+q][lrow] = (c<K)? Wg[(size_t)og*K+c] : 0.f;
      }
    }
    __syncthreads();
#pragma unroll
    for(int c=0;c<16;c++){
      float4 a4=*(const float4*)&As[c][ty<<2];
      float av[4]={a4.x,a4.y,a4.z,a4.w};
      float bw[CW];
#pragma unroll
      for(int j0=0;j0<CW;j0+=4){
        float4 b4=*(const float4*)&Bs[c][tx*CW+j0];
        bw[j0]=b4.x; bw[j0+1]=b4.y; bw[j0+2]=b4.z; bw[j0+3]=b4.w;
      }
#pragma unroll
      for(int i=0;i<4;i++)
#pragma unroll
        for(int j=0;j<CW;j++) acc[i][j]+=av[i]*bw[j];
    }
  }
#pragma unroll
  for(int i=0;i<4;i++){
    int r=rowBase+(ty<<2)+i;
    int rb=r/mloc, rm=r-rb*mloc;
    size_t obase=(size_t)rb*oBS + (size_t)rm*N;
#pragma unroll
    for(int j=0;j<CW;j++){
      int o=colBase+tx*CW+j;
      float v=acc[i][j];
      if(RELU) v=fmaxf(v,0.f);
      out[obase+o]=v;
    }
  }
}

// ---------------------------------------------------------------- host
extern "C" void kernel_launch(void* const* d_in, const int* in_sizes, int n_in,
                              void* d_out, int out_size, void* d_ws, size_t ws_size,
                              hipStream_t stream) {
  (void)in_sizes; (void)n_in; (void)out_size; (void)ws_size;

  const int di[6] = {2,4,7,10,13,16};
  const int fi[6] = {-1,5,8,11,14,17};
  const int ti[6] = {3,6,9,12,15,18};

  const int midv[6]={45,96,192,384,768,1536};
  const int midp[6]={0,128,256,384,768,1536};
  const int cinv[6]={0,64,128,256,512,1024};
  const int coutv[6]={64,128,256,512,1024,2048};
  const int tkv[6]={1,3,3,3,3,1};
  const int Nv[6]={2048,1024,512,512,256,256};
  const int mv[6]={1024,512,512,256,256,128};
  const int Lv[6]={4,4,2,2,1,1};
  const int Tv[6]={4,2,2,1,1,1};
  const float rrv[6]={1.5f,3.f,3.f,6.f,6.f,6.f};

  float* ws=(float*)d_ws;
  size_t off=0;
  auto A=[&](size_t n)->float*{ float* p=ws+off; off+=(n+63)&~(size_t)63; return p; };
  auto Ah=[&](size_t n)->f16*{ return (f16*)A((n+1)/2); };

  int* flag=(int*)A(64);

  f16* W2h[6]; W2h[0]=nullptr;
  for(int l=1;l<6;l++) W2h[l]=Ah((size_t)midp[l]*3*cinv[l]);
  f16* Wth[6]; Wth[0]=nullptr;
  for(int l=1;l<6;l++) Wth[l]=Ah((size_t)coutv[l]*tkv[l]*midv[l]);
  float* Wd0=A(135);
  float* Wt0=A(2880);
  f16* fcwh=Ah(2097152);
  float* fcb=A(1024);

  float* X[7];
  X[0]=A(786432);
  for(int l=0;l<6;l++) X[l+1]=A((size_t)32*Tv[l]*mv[l]*3);

  float* FA=A(8388608);
  float* FB=A(8388608);
  float* F[7]; F[0]=nullptr;
  for(int l=0;l<6;l++) F[l+1]=(l%2==0)?FA:FB;

  float* nf=A(18874368);
  float* sumsAll=A(11*2*2304);
  float* scb=A(2*2304);
  f16* Gh=Ah(12582912);
  int* bqAll=(int*)A(442368);

  // ---- detect dtype
  k_detect<<<dim3(1),dim3(256),0,stream>>>((const unsigned int*)d_in[0], 4096, flag);

  // ---- fused converts
  {
    CvtF32 J;
    J.src[0]=d_in[0];  J.dst[0]=X[0];  J.n[0]=786432;
    J.src[1]=d_in[3];  J.dst[1]=Wt0;   J.n[1]=2880;
    J.src[2]=d_in[20]; J.dst[2]=fcb;   J.n[2]=1024;
    J.src[3]=d_in[2];  J.dst[3]=Wd0;   J.n[3]=135;
    J.blk0[0]=0; J.blk0[1]=3072; J.blk0[2]=3084; J.blk0[3]=3088; J.blk0[4]=3089;
    k_cvt_all<<<dim3(3089),dim3(256),0,stream>>>(J,flag);
  }
  {
    CvtF16 J;
    int ns[6]={36864,147456,589824,2359296,3145728,2097152};
    const void* ss[6]={d_in[ti[1]],d_in[ti[2]],d_in[ti[3]],d_in[ti[4]],d_in[ti[5]],d_in[19]};
    f16* ds[6]={Wth[1],Wth[2],Wth[3],Wth[4],Wth[5],fcwh};
    int bp=0;
    for(int j2=0;j2<6;j2++){ J.src[j2]=ss[j2]; J.dst[j2]=ds[j2]; J.n[j2]=ns[j2]; J.blk0[j2]=bp; bp+=(ns[j2]+255)/256; }
    J.blk0[6]=bp;
    k_cvth_all<<<dim3((unsigned)bp),dim3(256),0,stream>>>(J,flag);
  }
  k_zero<<<dim3((11*2*2304+255)/256),256,0,stream>>>(sumsAll,11*2*2304);

  // ---- W2 per layer
  for(int l=1;l<6;l++){
    int tot=midp[l]*3*cinv[l];
    k_w2<<<dim3((unsigned)((tot+255)/256)),dim3(256),0,stream>>>(
        d_in[di[l]], d_in[fi[l]], W2h[l], midv[l], cinv[l], tot, flag);
  }

  struct PairT{int j,i;};
  const int Tcenters[6][4]={{0,1,2,3},{0,2,0,0},{0,1,0,0},{0,0,0,0},{0,0,0,0},{0,0,0,0}};
  const int npairs[6][4]={{1,1,1,1},{2,3,0,0},{2,2,0,0},{2,0,0,0},{1,0,0,0},{1,0,0,0}};
  const PairT pr[6][4][3]={
    { {{0,0},{0,0},{0,0}}, {{0,1},{0,0},{0,0}}, {{0,2},{0,0},{0,0}}, {{0,3},{0,0},{0,0}} },
    { {{1,0},{2,1},{0,0}}, {{0,1},{1,2},{2,3}}, {{0,0},{0,0},{0,0}}, {{0,0},{0,0},{0,0}} },
    { {{1,0},{2,1},{0,0}}, {{0,0},{1,1},{0,0}}, {{0,0},{0,0},{0,0}}, {{0,0},{0,0},{0,0}} },
    { {{1,0},{2,1},{0,0}}, {{0,0},{0,0},{0,0}}, {{0,0},{0,0},{0,0}}, {{0,0},{0,0},{0,0}} },
    { {{1,0},{0,0},{0,0}}, {{0,0},{0,0},{0,0}}, {{0,0},{0,0},{0,0}}, {{0,0},{0,0},{0,0}} },
    { {{0,0},{0,0},{0,0}}, {{0,0},{0,0},{0,0}}, {{0,0},{0,0},{0,0}}, {{0,0},{0,0},{0,0}} },
  };
  const int slotBase[6]={0,4,6,8,9,10};

  for(int l=0;l<6;l++){
    int N=Nv[l], m=mv[l], Lin=Lv[l], T=Tv[l], cin=cinv[l], mid=midv[l];
    int C=tkv[l]*midv[l], M=32*m, cout=coutv[l];
    float r2=rrv[l]*rrv[l];
    const float* Xin=X[l]; float* Xout=X[l+1];

    {
      dim3 g(32*T), blk(64);
      int a0=Tcenters[l][0],a1=Tcenters[l][1],a2=Tcenters[l][2],a3=Tcenters[l][3];
      if(N==2048)      k_fps3<32><<<g,blk,0,stream>>>(Xin,Lin,N,m,a0,a1,a2,a3,T,Xout);
      else if(N==1024) k_fps3<16><<<g,blk,0,stream>>>(Xin,Lin,N,m,a0,a1,a2,a3,T,Xout);
      else if(N==512)  k_fps3<8><<<g,blk,0,stream>>>(Xin,Lin,N,m,a0,a1,a2,a3,T,Xout);
      else             k_fps3<4><<<g,blk,0,stream>>>(Xin,Lin,N,m,a0,a1,a2,a3,T,Xout);
    }

    for(int tt=0; tt<T; ++tt){
      int np=npairs[l][tt];
      Pairs P;
      int jmask=0;
      for(int pi=0;pi<3;pi++){
        if(pi<np){ P.j[pi]=pr[l][tt][pi].j; P.i[pi]=pr[l][tt][pi].i; jmask|=1<<P.j[pi]; }
        else { P.j[pi]=0; P.i[pi]=0; }
      }
      const float* anc = Xout + (size_t)tt*m*3;
      size_t aBS=(size_t)T*m*3;
      int chunks=(m+255)>>8;
      k_bq<<<dim3(32*chunks,np),256,0,stream>>>(Xin,anc,bqAll,N,m,r2,Lin,aBS,P);
      if(l==0){
        const float* pts = Xin + (size_t)tt*N*3;
        k_part0<<<dim3(M),64,0,stream>>>(pts,anc,bqAll,Wd0,nf,m,mid,C,N-1,(size_t)Lin*N*3,aBS);
      } else {
        int cw = cin<256? cin:256;
        int rpb = 256/cw;
        k_outer<<<dim3((unsigned)(np*M/rpb)),256,0,stream>>>(
            F[l],Xin,anc,bqAll,Gh,m,cin,N,Lin,aBS,N-1,P);
        k_pg<<<dim3((unsigned)(np*M/128),(unsigned)(midp[l]/128)),256,0,stream>>>(
            Gh,W2h[l],nf,3*cin,mid,C,M,P);
      }
      float* sums=sumsAll+(size_t)(slotBase[l]+tt)*2*2304;
      k_bnstat<<<dim3((C+255)/256,32),256,0,stream>>>(nf,M,C,sums,mid,jmask);
      k_bnfin<<<dim3((C+255)/256),256,0,stream>>>(sums,scb,C,M,mid,jmask);
      float* outp = F[l+1] + (size_t)tt*m*cout;
      size_t oBS=(size_t)T*m*cout;
      if(l==0)
        k_gemm<64,true><<<dim3(M/64,cout/64),256,0,stream>>>(nf,Wt0,outp,M,C,cout,m,oBS,scb);
      else if(l<5)
        k_gemm_mfma<true,false,true><<<dim3(M/128,cout/128),256,0,stream>>>(
            nf,Wth[l],nullptr,outp,M,C,cout,m,oBS,nullptr,scb);
      else
        k_gemm_mfma<false,false,true><<<dim3(M/128,cout/128),256,0,stream>>>(
            nf,Wth[l],nullptr,outp,M,C,cout,m,oBS,nullptr,scb);
    }
  }

  k_gemm_mfma<false,true,false><<<dim3(4096/128,1024/128),256,0,stream>>>(
      F[6],fcwh,fcb,d_out,4096,2048,1024,128,(size_t)128*1024,flag,nullptr);
}

// Round 7
// 3173.537 us; speedup vs baseline: 2.4176x; 1.7048x over previous
//
#include <hip/hip_runtime.h>
#include <hip/hip_bf16.h>
#include <math.h>

typedef __hip_bfloat16 bf16;
typedef _Float16 f16;
typedef _Float16 f16x2 __attribute__((ext_vector_type(2)));
typedef _Float16 f16x8 __attribute__((ext_vector_type(8)));
typedef float f32x4 __attribute__((ext_vector_type(4)));

struct Sched { int tt[5]; int fi[5]; int jj[5]; };
struct CvtF32 { const void* src[4]; float* dst[4]; int n[4]; int blk0[5]; };
struct CvtF16 { const void* src[6]; f16* dst[6]; int n[6]; int blk0[7]; };
struct W2J { const void* wd[5]; const void* wf[5]; f16* dst[5]; int mid[5]; int cin[5]; int n[5]; int blk0[6]; };

// ---------------------------------------------------------------- dtype detect
__global__ void k_detect(const unsigned int* __restrict__ w, int nwords, int* __restrict__ flag){
  __shared__ int cnt;
  if(threadIdx.x==0) cnt=0;
  __syncthreads();
  int local=0;
  for(int i=threadIdx.x;i<nwords;i+=256){
    unsigned int v=w[i];
    int e=(v>>7)&0xFF;
    if(e>=0xC0) local++;
  }
  atomicAdd(&cnt, local);
  __syncthreads();
  if(threadIdx.x==0) flag[0] = (cnt > (nwords>>3)) ? 1 : 0;
}

__device__ inline float ldmix(const void* p, size_t i, bool f32m){
  return f32m ? ((const float*)p)[i] : __bfloat162float(((const bf16*)p)[i]);
}

// ---------------------------------------------------------------- fused converts
__global__ void k_cvt_all(CvtF32 J, const int* __restrict__ flag){
  int b=blockIdx.x;
  int j=0;
  while(j<3 && J.blk0[j+1]<=b) j++;
  int i=(b-J.blk0[j])*256+threadIdx.x;
  if(i>=J.n[j]) return;
  bool f32m=*flag!=0;
  J.dst[j][i]=ldmix(J.src[j],i,f32m);
}

__global__ void k_cvth_all(CvtF16 J, const int* __restrict__ flag){
  int b=blockIdx.x;
  int j=0;
  while(j<5 && J.blk0[j+1]<=b) j++;
  int i=(b-J.blk0[j])*256+threadIdx.x;
  if(i>=J.n[j]) return;
  bool f32m=*flag!=0;
  J.dst[j][i]=(f16)ldmix(J.src[j],i,f32m);
}

__global__ void k_zero(float* __restrict__ p, int n){
  int i = blockIdx.x*256 + threadIdx.x;
  if(i<n) p[i]=0.f;
}

// W2[o, a*cin+c] = Wd[o,a]*Wf[o,c], all 5 layers in one launch
__global__ void k_w2all(W2J J, const int* __restrict__ flag){
  int b=blockIdx.x;
  int j=0;
  while(j<4 && J.blk0[j+1]<=b) j++;
  int i=(b-J.blk0[j])*256+threadIdx.x;
  if(i>=J.n[j]) return;
  int cin=J.cin[j]; int K3=3*cin;
  int o=i/K3; int rem=i-o*K3; int a=rem/cin; int c=rem-a*cin;
  float v=0.f;
  if(o<J.mid[j]){
    bool f32m=*flag!=0;
    v=ldmix(J.wd[j],(size_t)3*o+a,f32m)*ldmix(J.wf[j],(size_t)o*cin+c,f32m);
  }
  J.dst[j][i]=(f16)v;
}

// ---------------------------------------------------------------- FPS: 256 threads, DPP in-wave argmax (round-5 proven)
template<int P>
__global__ __launch_bounds__(256) void k_fps2(
    const float* __restrict__ xyz, int L, int N, int m,
    int c0,int c1,int c2,int c3, int T, float* __restrict__ anchors)
{
  __shared__ float4 ptsS[P*256];
  __shared__ unsigned long long keyS[2][4];
  int prob=blockIdx.x;
  int b=prob/T, tt=prob%T;
  int f=(tt==0)?c0:(tt==1)?c1:(tt==2)?c2:c3;
  const float* src = xyz + ((size_t)(b*L+f))*N*3;
  float* anc = anchors + ((size_t)(b*T+tt))*m*3;
  int tid=threadIdx.x;
  for(int t=tid;t<N;t+=256)
    ptsS[t]=make_float4(src[3*t],src[3*t+1],src[3*t+2],0.f);
  __syncthreads();
  float px[P],py[P],pz[P],mind[P];
#pragma unroll
  for(int j=0;j<P;j++){
    float4 v=ptsS[tid+j*256];
    px[j]=v.x; py[j]=v.y; pz[j]=v.z; mind[j]=1e10f;
  }
  float4 p0=ptsS[0];
  float lx=p0.x, ly=p0.y, lz=p0.z;
  if(tid==0){ anc[0]=lx; anc[1]=ly; anc[2]=lz; }
  int w=tid>>6;
  for(int it=1; it<m; ++it){
    float bv=-1.f; int bi=0;
#pragma unroll
    for(int j=0;j<P;j++){
#pragma clang fp contract(off)
      float dx=px[j]-lx, dy=py[j]-ly, dz=pz[j]-lz;
      float d2=dx*dx+dy*dy+dz*dz;
      float mv=mind[j]; if(d2<mv) mv=d2; mind[j]=mv;
      if(mv>bv){ bv=mv; bi=tid+j*256; }
    }
    unsigned int hi=__float_as_uint(bv);
    unsigned int lo=0xFFFFFFFFu-(unsigned)bi;
#define DPPSTEP(CTRL) { \
    unsigned int shi=(unsigned)__builtin_amdgcn_update_dpp(0,(int)hi,CTRL,0xF,0xF,true); \
    unsigned int slo=(unsigned)__builtin_amdgcn_update_dpp(0,(int)lo,CTRL,0xF,0xF,true); \
    bool g=(shi>hi)||(shi==hi&&slo>lo); \
    hi=g?shi:hi; lo=g?slo:lo; }
    DPPSTEP(0x111) DPPSTEP(0x112) DPPSTEP(0x114) DPPSTEP(0x118) DPPSTEP(0x142) DPPSTEP(0x143)
#undef DPPSTEP
    if((tid&63)==63)
      keyS[it&1][w]=((unsigned long long)hi<<32)|lo;
    __syncthreads();
    unsigned long long k0=keyS[it&1][0], k1=keyS[it&1][1];
    unsigned long long k2=keyS[it&1][2], k3=keyS[it&1][3];
    unsigned long long ka = k0>k1?k0:k1;
    unsigned long long kb = k2>k3?k2:k3;
    unsigned long long kk = ka>kb?ka:kb;
    int wi = (int)(0xFFFFFFFFu - (unsigned)(kk & 0xFFFFFFFFull));
    float4 wc = ptsS[wi];
    lx=wc.x; ly=wc.y; lz=wc.z;
    if(tid==0){ anc[3*it]=lx; anc[3*it+1]=ly; anc[3*it+2]=lz; }
  }
}

// ---------------------------------------------------------------- ball query, batched over all slots of a layer
__global__ __launch_bounds__(256) void k_bq(
    const float* __restrict__ Xin, const float* __restrict__ Xout,
    int* __restrict__ bqAll, int N, int m, float r2, int Lin, size_t aBS, int M, Sched S)
{
  int chunks=(m+255)>>8;
  int b=blockIdx.x/chunks;
  int a=(blockIdx.x%chunks)*256+threadIdx.x;
  int s=blockIdx.y;
  int tt=S.tt[s], fr=S.fi[s];
  const float* Pb = Xin + ((size_t)b*Lin + fr)*(size_t)N*3;
  bool act = a<m;
  float ax=0,ay=0,az=0;
  int* o = bqAll + ((size_t)s*M + (size_t)b*m + (size_t)(act?a:0))*9;
  if(act){
    const float* A=Xout+(size_t)b*aBS+(size_t)tt*m*3+(size_t)a*3;
    ax=A[0]; ay=A[1]; az=A[2];
  }
  int cnt = act?0:9, first=0;
  __shared__ float sp[768];
  for(int base=0; base<N; base+=256){
    for(int t=threadIdx.x; t<768; t+=256) sp[t]=Pb[(size_t)base*3+t];
    __syncthreads();
    for(int q=0;q<256;q++){
#pragma clang fp contract(off)
      float dx=sp[3*q]-ax, dy=sp[3*q+1]-ay, dz=sp[3*q+2]-az;
      float d2=dx*dx+dy*dy+dz*dz;
      if(d2<r2 && cnt<9){
        int p=base+q;
        if(cnt==0) first=p;
        o[cnt]=p; cnt++;
      }
    }
    if(__syncthreads_and(cnt>=9)) break;
  }
  if(act){ for(int k=cnt;k<9;k++) o[k]=first; }
}

// ---------------------------------------------------------------- layer 0 (cin=0): nf = sum_k disp_k . Wd  (batched over tt)
__global__ void k_part0(
    const float* __restrict__ Xin, const float* __restrict__ Xout,
    const int* __restrict__ bqAll, const float* __restrict__ Wd,
    f16* __restrict__ nfh, int m, int mid, int ld, int nmask,
    size_t aBS, int N, int Lin, int M, Sched S)
{
  int row = blockIdx.x;
  int tt = blockIdx.y;                      // l0: slot == tt
  int b = row/m, mm = row - b*m;
  const float* A = Xout + (size_t)b*aBS + (size_t)tt*m*3 + (size_t)mm*3;
  float ax=A[0], ay=A[1], az=A[2];
  int o = threadIdx.x;
  float w0=0,w1=0,w2=0;
  if(o<mid){ w0=Wd[3*o]; w1=Wd[3*o+1]; w2=Wd[3*o+2]; }
  int fr=S.fi[tt];
  const int* id = bqAll + ((size_t)tt*M + row)*9;
  const float* Pb = Xin + ((size_t)b*Lin+fr)*(size_t)N*3;
  float acc=0.f;
  for(int k=0;k<9;k++){
    int p=id[k] & nmask;
    const float* q = Pb + (size_t)p*3;
    float dx=q[0]-ax, dy=q[1]-ay, dz=q[2]-az;
    acc += dx*w0+dy*w1+dz*w2;
  }
  if(o<mid) nfh[(size_t)tt*M*ld + (size_t)row*ld + o] = (f16)acc;
}

// ---------------------------------------------------------------- G[r, a*cin+c] = sum_k disp[r,k,a]*fg[r,k,c]  (batched)
__global__ __launch_bounds__(256) void k_outer(
    const f16* __restrict__ feats, const float* __restrict__ Xin,
    const float* __restrict__ Xout, const int* __restrict__ bqAll,
    f16* __restrict__ Gh, int m, int cin, int N, int Lin,
    size_t aBS, int nmask, int M, Sched S)
{
  int cw2 = cin>>1; if(cw2>256) cw2=256;
  int rpb = 256/cw2;
  int tid=threadIdx.x;
  int sub=tid/cw2, lc=tid-sub*cw2;
  int r=blockIdx.x*rpb+sub;
  int Kp=3*cin;
  int s=r/M, mrow=r-s*M;
  int b=mrow/m, mm=mrow-b*m;
  int tt=S.tt[s], fr=S.fi[s];
  const float* A0=Xout+(size_t)b*aBS+(size_t)tt*m*3+(size_t)mm*3;
  float ax=A0[0],ay=A0[1],az=A0[2];
  const float* Pb=Xin+((size_t)b*Lin+fr)*(size_t)N*3;
  const f16* Fb=feats+(((size_t)b*Lin+fr)*(size_t)N)*(size_t)cin;
  const int* id=bqAll+(size_t)r*9;
  int idx[9]; float d0[9],d1[9],d2a[9];
#pragma unroll
  for(int k=0;k<9;k++){
    int p=id[k]&nmask; idx[k]=p;
    const float* q=Pb+(size_t)p*3;
    d0[k]=q[0]-ax; d1[k]=q[1]-ay; d2a[k]=q[2]-az;
  }
  f16* Gr=Gh+(size_t)r*Kp;
  for(int cc=2*lc; cc<cin; cc+=2*cw2){
    float a0=0,a1=0,a2=0,b0=0,b1=0,b2=0;
#pragma unroll
    for(int k=0;k<9;k++){
      f16x2 fv=*(const f16x2*)(Fb+(size_t)idx[k]*cin+cc);
      float f0=(float)fv[0], f1=(float)fv[1];
      a0=fmaf(d0[k],f0,a0); b0=fmaf(d0[k],f1,b0);
      a1=fmaf(d1[k],f0,a1); b1=fmaf(d1[k],f1,b1);
      a2=fmaf(d2a[k],f0,a2); b2=fmaf(d2a[k],f1,b2);
    }
    f16x2 o0={(f16)a0,(f16)b0}, o1={(f16)a1,(f16)b1}, o2={(f16)a2,(f16)b2};
    *(f16x2*)(Gr+cc)=o0; *(f16x2*)(Gr+cin+cc)=o1; *(f16x2*)(Gr+2*cin+cc)=o2;
  }
}

// ---------------------------------------------------------------- pair GEMM: nf[tt][mrow, j*mid+col] = G @ W2^T (batched)
__global__ __launch_bounds__(256) void k_pg(
    const f16* __restrict__ Gh, const f16* __restrict__ W2,
    f16* __restrict__ nfh, int Kp, int mid, int C, int M, Sched S)
{
  __shared__ f16 As[128*40];
  __shared__ f16 Bs[128*40];
  int tid=threadIdx.x;
  int lane=tid&63, w=tid>>6;
  int quad=lane>>4, l15=lane&15;
  int rowOff=(w>>1)*64, colOff=(w&1)*64;
  int rowBase=blockIdx.x*128, colBase=blockIdx.y*128;
  f32x4 acc[4][4];
#pragma unroll
  for(int i=0;i<4;i++)
#pragma unroll
    for(int j=0;j<4;j++) acc[i][j]=(f32x4){0.f,0.f,0.f,0.f};
  int nct=Kp>>5;
  int srow=tid>>1, shalf=tid&1;
  for(int ct=0;ct<nct;ct++){
    __syncthreads();
    {
      const uint4* s=(const uint4*)(Gh+(size_t)(rowBase+srow)*Kp+(ct<<5)+(shalf<<4));
      uint4 u0=s[0], u1=s[1];
      *(uint4*)(As + srow*40 + (shalf<<4))     = u0;
      *(uint4*)(As + srow*40 + (shalf<<4) + 8) = u1;
    }
    {
      const uint4* s=(const uint4*)(W2+(size_t)(colBase+srow)*Kp+(ct<<5)+(shalf<<4));
      uint4 u0=s[0], u1=s[1];
      *(uint4*)(Bs + srow*40 + (shalf<<4))     = u0;
      *(uint4*)(Bs + srow*40 + (shalf<<4) + 8) = u1;
    }
    __syncthreads();
    f16x8 af[4], bf4[4];
#pragma unroll
    for(int rt=0;rt<4;rt++) af[rt]=*(const f16x8*)(As + (rowOff+rt*16+l15)*40 + quad*8);
#pragma unroll
    for(int ctl=0;ctl<4;ctl++) bf4[ctl]=*(const f16x8*)(Bs + (colOff+ctl*16+l15)*40 + quad*8);
#pragma unroll
    for(int rt=0;rt<4;rt++)
#pragma unroll
      for(int ctl=0;ctl<4;ctl++)
        acc[rt][ctl]=__builtin_amdgcn_mfma_f32_16x16x32_f16(af[rt],bf4[ctl],acc[rt][ctl],0,0,0);
  }
#pragma unroll
  for(int rt=0;rt<4;rt++){
#pragma unroll
    for(int r=0;r<4;r++){
      int row=rowBase+rowOff+rt*16+quad*4+r;
      int s=row/M, mrow=row-s*M;
      int tt=S.tt[s], j=S.jj[s];
      f16* base = nfh + (size_t)tt*M*C + (size_t)mrow*C + j*mid;
#pragma unroll
      for(int ctl=0;ctl<4;ctl++){
        int col=colBase+colOff+ctl*16+l15;
        if(col<mid) base[col]=(f16)acc[rt][ctl][r];
      }
    }
  }
}

// ---------------------------------------------------------------- BN stats (batched over tt, jmask skips unwritten slices)
__global__ void k_bnstat(const f16* __restrict__ nfh, int M, int C, float* __restrict__ sumsL,
                         int mid, int4 jm, int sumStride){
  int c = blockIdx.x*256 + threadIdx.x;
  if(c>=C) return;
  int tt=blockIdx.z;
  int jmask = (tt==0)?jm.x:(tt==1)?jm.y:(tt==2)?jm.z:jm.w;
  int j=c/mid;
  if(!((jmask>>j)&1)) return;
  const f16* base=nfh+(size_t)tt*M*C;
  int rows = M>>5;
  int r0 = blockIdx.y*rows, r1 = r0+rows;
  float s=0.f, s2=0.f;
  for(int r=r0;r<r1;r++){
    float v=(float)base[(size_t)r*C+c];
    s+=v; s2+=v*v;
  }
  atomicAdd(&sumsL[tt*sumStride+c], s);
  atomicAdd(&sumsL[tt*sumStride+C+c], s2);
}

__global__ void k_bnfin(const float* __restrict__ sumsL, float* __restrict__ scbAll,
                        int C, int M, int mid, int4 jm, int sumStride, int scbStride){
  int c = blockIdx.x*256 + threadIdx.x;
  if(c>=C) return;
  int tt=blockIdx.y;
  int jmask = (tt==0)?jm.x:(tt==1)?jm.y:(tt==2)?jm.z:jm.w;
  float* scb=scbAll+(size_t)tt*scbStride;
  int j=c/mid;
  if(!((jmask>>j)&1)){ scb[c]=0.f; scb[C+c]=0.f; return; }
  float mean=sumsL[tt*sumStride+c]/(float)M;
  float var=sumsL[tt*sumStride+C+c]/(float)M - mean*mean;
  if(var<0.f) var=0.f;
  float rs=1.0f/sqrtf(var+1e-5f);
  scb[c]=rs; scb[C+c]=-mean*rs;
}

// ---------------------------------------------------------------- MFMA GEMM, A=f16 (opt fused BN+ReLU on A), batched over tt
template<bool RELU, bool DYN, bool BNA>
__global__ __launch_bounds__(256) void k_gemm_mfma(
    const f16* __restrict__ Ag, const f16* __restrict__ Bh,
    const float* __restrict__ bias, void* __restrict__ out,
    int K, int N, int mloc, size_t oBS, size_t ttA, size_t ttO,
    const int* __restrict__ oflag, const float* __restrict__ scbAll, int scbStride)
{
  __shared__ f16 As[128*40];
  __shared__ f16 Bs[128*40];
  int tid=threadIdx.x;
  int lane=tid&63, w=tid>>6;
  int quad=lane>>4, l15=lane&15;
  int rowOff=(w>>1)*64, colOff=(w&1)*64;
  int rowBase=blockIdx.x*128, colBase=blockIdx.y*128;
  int tt=blockIdx.z;
  const f16* A0=Ag+(size_t)tt*ttA;
  const float* scb = BNA ? (scbAll+(size_t)tt*scbStride) : nullptr;
  f32x4 acc[4][4];
#pragma unroll
  for(int i=0;i<4;i++)
#pragma unroll
    for(int j=0;j<4;j++) acc[i][j]=(f32x4){0.f,0.f,0.f,0.f};
  int nct=K>>5;
  int srow=tid>>1, shalf=tid&1;
  for(int ct=0;ct<nct;ct++){
    __syncthreads();
    {
      int c0g=(ct<<5)+(shalf<<4);
      const f16* src=A0+(size_t)(rowBase+srow)*K+c0g;
      if(BNA){
        f16x8 x0=((const f16x8*)src)[0], x1=((const f16x8*)src)[1];
        f16x8 h0,h1;
#pragma unroll
        for(int q=0;q<8;q++){
          h0[q]=(f16)fmaxf(fmaf((float)x0[q],scb[c0g+q],scb[K+c0g+q]),0.f);
          h1[q]=(f16)fmaxf(fmaf((float)x1[q],scb[c0g+8+q],scb[K+c0g+8+q]),0.f);
        }
        *(f16x8*)(As+srow*40+(shalf<<4))=h0;
        *(f16x8*)(As+srow*40+(shalf<<4)+8)=h1;
      } else {
        const uint4* s=(const uint4*)src;
        uint4 u0=s[0],u1=s[1];
        *(uint4*)(As+srow*40+(shalf<<4))=u0;
        *(uint4*)(As+srow*40+(shalf<<4)+8)=u1;
      }
    }
    {
      const uint4* s=(const uint4*)(Bh+(size_t)(colBase+srow)*K+(ct<<5)+(shalf<<4));
      uint4 u0=s[0], u1=s[1];
      *(uint4*)(Bs + srow*40 + (shalf<<4))     = u0;
      *(uint4*)(Bs + srow*40 + (shalf<<4) + 8) = u1;
    }
    __syncthreads();
    f16x8 af[4], bf4[4];
#pragma unroll
    for(int rt=0;rt<4;rt++) af[rt]=*(const f16x8*)(As + (rowOff+rt*16+l15)*40 + quad*8);
#pragma unroll
    for(int ctl=0;ctl<4;ctl++) bf4[ctl]=*(const f16x8*)(Bs + (colOff+ctl*16+l15)*40 + quad*8);
#pragma unroll
    for(int rt=0;rt<4;rt++)
#pragma unroll
      for(int ctl=0;ctl<4;ctl++)
        acc[rt][ctl]=__builtin_amdgcn_mfma_f32_16x16x32_f16(af[rt],bf4[ctl],acc[rt][ctl],0,0,0);
  }
  bool f32m = DYN ? (*oflag!=0) : true;
#pragma unroll
  for(int rt=0;rt<4;rt++){
#pragma unroll
    for(int r=0;r<4;r++){
      int row=rowBase+rowOff+rt*16+quad*4+r;
      int rb=row/mloc, rm=row-rb*mloc;
      size_t obase=(size_t)rb*oBS + (size_t)tt*ttO + (size_t)rm*N;
#pragma unroll
      for(int ctl=0;ctl<4;ctl++){
        int col=colBase+colOff+ctl*16+l15;
        float v=acc[rt][ctl][r];
        if(bias) v+=bias[col];
        if(RELU) v=fmaxf(v,0.f);
        if(DYN){
          if(!f32m) ((bf16*)out)[obase+col]=__float2bfloat16(v);
          else      ((float*)out)[obase+col]=v;
        } else {
          ((f16*)out)[obase+col]=(f16)v;
        }
      }
    }
  }
}

// ---------------------------------------------------------------- f32 GEMM (layer 0 temporal, K=45), BN fused, batched over tt
__global__ __launch_bounds__(256) void k_gemm0(
    const f16* __restrict__ nfh, const float* __restrict__ Wg,
    f16* __restrict__ out, int M, int K, int N, int mloc, size_t oBS, size_t ttO,
    const float* __restrict__ scbAll, int scbStride)
{
  __shared__ alignas(16) float As[16][64];
  __shared__ alignas(16) float Bs[16][64];
  int tid=threadIdx.x, tx=tid&15, ty=tid>>4;
  int rowBase=blockIdx.x*64, colBase=blockIdx.y*64;
  int tt=blockIdx.z;
  const f16* A0=nfh+(size_t)tt*M*K;
  const float* scb=scbAll+(size_t)tt*scbStride;
  float acc[4][4];
#pragma unroll
  for(int i=0;i<4;i++)
#pragma unroll
    for(int j=0;j<4;j++) acc[i][j]=0.f;
  int lrow=tid&63, lcq=tid>>6;
  int nct=(K+15)>>4;
  for(int ct=0;ct<nct;ct++){
    __syncthreads();
    {
      int r=rowBase+lrow, c0=(ct<<4)+(lcq<<2);
#pragma unroll
      for(int q=0;q<4;q++){
        int c=c0+q;
        As[(lcq<<2)+q][lrow] = (c<K)? fmaxf(fmaf((float)A0[(size_t)r*K+c],scb[c],scb[K+c]),0.f) : 0.f;
      }
    }
    {
      int og=colBase+lrow, c0=(ct<<4)+(lcq<<2);
#pragma unroll
      for(int q=0;q<4;q++){
        int c=c0+q;
        Bs[(lcq<<2)+q][lrow] = (c<K)? Wg[(size_t)og*K+c] : 0.f;
      }
    }
    __syncthreads();
#pragma unroll
    for(int c=0;c<16;c++){
      float4 a4=*(const float4*)&As[c][ty<<2];
      float av[4]={a4.x,a4.y,a4.z,a4.w};
      float4 b4=*(const float4*)&Bs[c][tx<<2];
      float bw[4]={b4.x,b4.y,b4.z,b4.w};
#pragma unroll
      for(int i=0;i<4;i++)
#pragma unroll
        for(int j=0;j<4;j++) acc[i][j]+=av[i]*bw[j];
    }
  }
#pragma unroll
  for(int i=0;i<4;i++){
    int r=rowBase+(ty<<2)+i;
    int rb=r/mloc, rm=r-rb*mloc;
    size_t obase=(size_t)rb*oBS + (size_t)blockIdx.z*ttO + (size_t)rm*N;
#pragma unroll
    for(int j=0;j<4;j++){
      int o=colBase+(tx<<2)+j;
      out[obase+o]=(f16)fmaxf(acc[i][j],0.f);
    }
  }
}

// ---------------------------------------------------------------- host
extern "C" void kernel_launch(void* const* d_in, const int* in_sizes, int n_in,
                              void* d_out, int out_size, void* d_ws, size_t ws_size,
                              hipStream_t stream) {
  (void)in_sizes; (void)n_in; (void)out_size; (void)ws_size;

  const int di[6] = {2,4,7,10,13,16};
  const int fi6[6] = {-1,5,8,11,14,17};
  const int ti[6] = {3,6,9,12,15,18};

  const int midv[6]={45,96,192,384,768,1536};
  const int midp[6]={0,128,256,384,768,1536};
  const int cinv[6]={0,64,128,256,512,1024};
  const int coutv[6]={64,128,256,512,1024,2048};
  const int tkv[6]={1,3,3,3,3,1};
  const int Nv[6]={2048,1024,512,512,256,256};
  const int mv[6]={1024,512,512,256,256,128};
  const int Lv[6]={4,4,2,2,1,1};
  const int Tv[6]={4,2,2,1,1,1};
  const float rrv[6]={1.5f,3.f,3.f,6.f,6.f,6.f};

  float* ws=(float*)d_ws;
  size_t off=0;
  auto A=[&](size_t n)->float*{ float* p=ws+off; off+=(n+63)&~(size_t)63; return p; };
  auto Ah=[&](size_t n)->f16*{ return (f16*)A((n+1)/2); };

  int* flag=(int*)A(64);

  f16* W2h[6]; W2h[0]=nullptr;
  for(int l=1;l<6;l++) W2h[l]=Ah((size_t)midp[l]*3*cinv[l]);
  f16* Wth[6]; Wth[0]=nullptr;
  for(int l=1;l<6;l++) Wth[l]=Ah((size_t)coutv[l]*tkv[l]*midv[l]);
  float* Wd0=A(135);
  float* Wt0=A(2880);
  f16* fcwh=Ah(2097152);
  float* fcb=A(1024);

  float* X[7];
  X[0]=A(786432);
  for(int l=0;l<6;l++) X[l+1]=A((size_t)32*Tv[l]*mv[l]*3);

  f16* FA=Ah(8388608);
  f16* FB=Ah(8388608);
  f16* F[7]; F[0]=nullptr;
  for(int l=0;l<6;l++) F[l+1]=(l%2==0)?FA:FB;

  f16* nfh=Ah(18874368);           // max T*M*C (l2/l4: 18.87M)
  float* sumsAll=A(11*4608);
  float* scbAll=A(4*4608);
  f16* Gh=Ah(25165824);            // max SLOTS*M*Kp (l2: 25.2M)
  int* bqAll=(int*)A(1179648);     // max SLOTS*M*9 (l0: 1.18M)

  // ---- setup: detect + converts + W2 + zero sums (5 dispatches)
  k_detect<<<dim3(1),dim3(256),0,stream>>>((const unsigned int*)d_in[0], 4096, flag);
  {
    CvtF32 J;
    J.src[0]=d_in[0];  J.dst[0]=X[0];  J.n[0]=786432;
    J.src[1]=d_in[3];  J.dst[1]=Wt0;   J.n[1]=2880;
    J.src[2]=d_in[20]; J.dst[2]=fcb;   J.n[2]=1024;
    J.src[3]=d_in[2];  J.dst[3]=Wd0;   J.n[3]=135;
    J.blk0[0]=0; J.blk0[1]=3072; J.blk0[2]=3084; J.blk0[3]=3088; J.blk0[4]=3089;
    k_cvt_all<<<dim3(3089),dim3(256),0,stream>>>(J,flag);
  }
  {
    CvtF16 J;
    int ns[6]={36864,147456,589824,2359296,3145728,2097152};
    const void* ss[6]={d_in[ti[1]],d_in[ti[2]],d_in[ti[3]],d_in[ti[4]],d_in[ti[5]],d_in[19]};
    f16* ds[6]={Wth[1],Wth[2],Wth[3],Wth[4],Wth[5],fcwh};
    int bp=0;
    for(int j2=0;j2<6;j2++){ J.src[j2]=ss[j2]; J.dst[j2]=ds[j2]; J.n[j2]=ns[j2]; J.blk0[j2]=bp; bp+=(ns[j2]+255)/256; }
    J.blk0[6]=bp;
    k_cvth_all<<<dim3((unsigned)bp),dim3(256),0,stream>>>(J,flag);
  }
  {
    W2J J;
    int bp=0;
    for(int l=1;l<6;l++){
      int j2=l-1;
      J.wd[j2]=d_in[di[l]]; J.wf[j2]=d_in[fi6[l]]; J.dst[j2]=W2h[l];
      J.mid[j2]=midv[l]; J.cin[j2]=cinv[l]; J.n[j2]=midp[l]*3*cinv[l];
      J.blk0[j2]=bp; bp+=(J.n[j2]+255)/256;
    }
    J.blk0[5]=bp;
    k_w2all<<<dim3((unsigned)bp),dim3(256),0,stream>>>(J,flag);
  }
  k_zero<<<dim3((11*4608+255)/256),256,0,stream>>>(sumsAll,11*4608);

  // ---- schedule tables
  const int SLOTS[6]={4,5,4,2,1,1};
  const int sTT[6][5]={{0,1,2,3,0},{0,0,1,1,1},{0,0,1,1,0},{0,0,0,0,0},{0,0,0,0,0},{0,0,0,0,0}};
  const int sFI[6][5]={{0,1,2,3,0},{0,1,1,2,3},{0,1,0,1,0},{0,1,0,0,0},{0,0,0,0,0},{0,0,0,0,0}};
  const int sJJ[6][5]={{0,0,0,0,0},{1,2,0,1,2},{1,2,0,1,0},{1,2,0,0,0},{1,0,0,0,0},{0,0,0,0,0}};
  const int4 jm4[6]={{1,1,1,1},{6,7,0,0},{6,3,0,0},{6,0,0,0},{2,0,0,0},{1,0,0,0}};
  const int Tcenters[6][4]={{0,1,2,3},{0,2,0,0},{0,1,0,0},{0,0,0,0},{0,0,0,0},{0,0,0,0}};
  const int slotBase[6]={0,4,6,8,9,10};

  for(int l=0;l<6;l++){
    int N=Nv[l], m=mv[l], Lin=Lv[l], T=Tv[l], cin=cinv[l], mid=midv[l];
    int C=tkv[l]*midv[l], M=32*m, cout=coutv[l];
    float r2=rrv[l]*rrv[l];
    const float* Xin=X[l]; float* Xout=X[l+1];

    { // FPS
      dim3 g(32*T), blk(256);
      int a0=Tcenters[l][0],a1=Tcenters[l][1],a2=Tcenters[l][2],a3=Tcenters[l][3];
      if(N==2048)      k_fps2<8><<<g,blk,0,stream>>>(Xin,Lin,N,m,a0,a1,a2,a3,T,Xout);
      else if(N==1024) k_fps2<4><<<g,blk,0,stream>>>(Xin,Lin,N,m,a0,a1,a2,a3,T,Xout);
      else if(N==512)  k_fps2<2><<<g,blk,0,stream>>>(Xin,Lin,N,m,a0,a1,a2,a3,T,Xout);
      else             k_fps2<1><<<g,blk,0,stream>>>(Xin,Lin,N,m,a0,a1,a2,a3,T,Xout);
    }

    Sched S;
    for(int s=0;s<5;s++){ S.tt[s]=sTT[l][s]; S.fi[s]=sFI[l][s]; S.jj[s]=sJJ[l][s]; }
    size_t aBS=(size_t)T*m*3;
    int chunks=(m+255)>>8;

    k_bq<<<dim3(32*chunks,SLOTS[l]),256,0,stream>>>(Xin,Xout,bqAll,N,m,r2,Lin,aBS,M,S);

    if(l==0){
      k_part0<<<dim3(M,4),64,0,stream>>>(Xin,Xout,bqAll,Wd0,nfh,m,mid,C,N-1,aBS,N,Lin,M,S);
    } else {
      int cw2=cin>>1; if(cw2>256) cw2=256;
      int rpb=256/cw2;
      k_outer<<<dim3((unsigned)(SLOTS[l]*M/rpb)),256,0,stream>>>(
          F[l],Xin,Xout,bqAll,Gh,m,cin,N,Lin,aBS,N-1,M,S);
      k_pg<<<dim3((unsigned)(SLOTS[l]*M/128),(unsigned)(midp[l]/128)),256,0,stream>>>(
          Gh,W2h[l],nfh,3*cin,mid,C,M,S);
    }

    float* sumsL=sumsAll+(size_t)slotBase[l]*4608;
    k_bnstat<<<dim3((C+255)/256,32,T),256,0,stream>>>(nfh,M,C,sumsL,mid,jm4[l],4608);
    k_bnfin<<<dim3((C+255)/256,T),256,0,stream>>>(sumsL,scbAll,C,M,mid,jm4[l],4608,4608);

    size_t oBS=(size_t)T*m*cout;
    size_t ttO=(size_t)m*cout;
    if(l==0)
      k_gemm0<<<dim3(M/64,1,4),256,0,stream>>>(nfh,Wt0,F[1],M,C,cout,m,oBS,ttO,scbAll,4608);
    else if(l<5)
      k_gemm_mfma<true,false,true><<<dim3(M/128,cout/128,T),256,0,stream>>>(
          nfh,Wth[l],nullptr,F[l+1],C,cout,m,oBS,(size_t)M*C,ttO,nullptr,scbAll,4608);
    else
      k_gemm_mfma<false,false,true><<<dim3(M/128,cout/128,T),256,0,stream>>>(
          nfh,Wth[l],nullptr,F[l+1],C,cout,m,oBS,(size_t)M*C,ttO,nullptr,scbAll,4608);
  }

  // final FC (A=F[6] f16, contiguous 4096x2048) -> d_out (bf16 or f32 per flag)
  k_gemm_mfma<false,true,false><<<dim3(4096/128,1024/128,1),256,0,stream>>>(
      F[6],fcwh,fcb,d_out,2048,1024,128,(size_t)128*1024,0,0,flag,nullptr,0);
}